// Round 12
// baseline (344.020 us; speedup 1.0000x reference)
//
#include <hip/hip_runtime.h>
#include <math.h>

typedef unsigned long long u64;
typedef _Float16 h2 __attribute__((ext_vector_type(2)));

#define N_PTS 12000
#define KNN 16
#define TJ 256     // candidate tile size
#define Q 2        // queries per wave
#define WPB 4      // waves per block (256-thread blocks)
#define QB (WPB * Q)                     // 8 queries per block
#define NTILES ((N_PTS + TJ - 1) / TJ)   // 47
#define TAU_TILES 8                      // sample = first 2048 points
#define CAP 384                          // survivor capacity; 6 offers/lane
#define HROW 12                          // u32 row stride per point (48 B, 16B-aligned)
#define MARGIN 0.08f                     // > 2*m, m = f16 d2 error bound ~0.032

// ---------------------------------------------------------------------------
// Kernel 1: encoders. feats = tanh(x@Wf+bf); coords = tanh(x@Wl+bl) fp32+f16;
// sq = |coords|^2. One wave per row.
// ---------------------------------------------------------------------------
__global__ __launch_bounds__(256) void encoder_kernel(
    const float* __restrict__ x, const float* __restrict__ Wf, const float* __restrict__ bf,
    const float* __restrict__ Wl, const float* __restrict__ bl,
    float* __restrict__ feats, float* __restrict__ coords, _Float16* __restrict__ coords_h,
    float* __restrict__ sq)
{
  const int wave = threadIdx.x >> 6;
  const int lane = threadIdx.x & 63;
  const int i = blockIdx.x * 4 + wave;
  if (i >= N_PTS) return;
  float xv = x[i * 64 + lane];
  float accf = bf[lane];
  float accc = bl[lane & 15];
  #pragma unroll
  for (int k = 0; k < 64; ++k) {
    float xk = __shfl(xv, k);
    accf = fmaf(xk, Wf[k * 64 + lane], accf);
    accc = fmaf(xk, Wl[k * 16 + (lane & 15)], accc);
  }
  feats[i * 64 + lane] = tanhf(accf);
  float c = tanhf(accc);
  float cc = (lane < 16) ? c * c : 0.0f;
  cc += __shfl_xor(cc, 1);
  cc += __shfl_xor(cc, 2);
  cc += __shfl_xor(cc, 4);
  cc += __shfl_xor(cc, 8);
  if (lane < 16) {
    coords[i * 16 + lane] = c;
    coords_h[i * 16 + lane] = (_Float16)c;
  }
  if (lane == 0) sq[i] = cc;
}

// ---------------------------------------------------------------------------
// u64-key helpers. Keys (f32bits(d2)<<32)|j unique; sentinels (0x7F00000t<<32)
// exceed any real key; ~0ull matches no slot.
// ---------------------------------------------------------------------------
__device__ __forceinline__ void ins6(u64 key, u64* k6, u64& kmax) {
  const u64 om = (key < kmax) ? kmax : ~0ull;
  #pragma unroll
  for (int t = 0; t < 6; ++t)
    k6[t] = (k6[t] == om) ? key : k6[t];
  u64 a = k6[0] > k6[1] ? k6[0] : k6[1];
  u64 b = k6[2] > k6[3] ? k6[2] : k6[3];
  u64 c = k6[4] > k6[5] ? k6[4] : k6[5];
  a = a > b ? a : b;
  kmax = a > c ? a : c;
}

__device__ __forceinline__ void ins8(u64 key, u64* k8, u64& kmax) {
  const u64 om = (key < kmax) ? kmax : ~0ull;
  #pragma unroll
  for (int t = 0; t < 8; ++t)
    k8[t] = (k8[t] == om) ? key : k8[t];
  u64 a = k8[0] > k8[1] ? k8[0] : k8[1];
  u64 b = k8[2] > k8[3] ? k8[2] : k8[3];
  u64 c = k8[4] > k8[5] ? k8[4] : k8[5];
  u64 d = k8[6] > k8[7] ? k8[6] : k8[7];
  a = a > b ? a : b;
  c = c > d ? c : d;
  kmax = a > c ? a : c;
}

__device__ __forceinline__ u64 shflx_u64(u64 v, int off) {
  int lo = __shfl_xor((int)(unsigned)v, off);
  int hi = __shfl_xor((int)(unsigned)(v >> 32), off);
  return ((u64)(unsigned)hi << 32) | (unsigned)lo;
}

__device__ __forceinline__ u64 minbfly(u64 m) {
  #pragma unroll
  for (int off = 32; off >= 1; off >>= 1) {
    u64 o = shflx_u64(m, off);
    m = (o < m) ? o : m;
  }
  return m;
}

// ---------------------------------------------------------------------------
// Kernel 2: KNN + gaussian aggregation + fused output GEMM.
// Block = 4 waves x 2 queries = 8 queries; 1500 blocks -> 6000 waves (73%
// occupancy ceiling vs round-10/11's 27% grid-limited occupancy).
// Phase A (f16 fdot2): per-lane min over 2048-pt sample; tau = 16th order
//   stat of lane minima + MARGIN (sound: exact-16th <= tau_a + m, so every
//   true member's approx d2 <= tau_a + 2m < gate).
// Phase B (f16 fdot2): full scan; approx d2 <= gate pushes u16 index.
// Phase C: exact fp32 re-score (reference-identical fmaf chain), exact
//   top-16 via 6-slot tables (<=6 offers/lane: no eviction) + minbfly;
//   feats/agg rows stashed in LDS.
// Epilogue: block GEMM out = concat(feats,agg)@Wo + bo (8 rows, 2 cols/thr).
// Only failure mode: survivor overflow -> flag -> fixup recomputes row+out.
// ---------------------------------------------------------------------------
__global__ __launch_bounds__(256) void knn_agg_kernel(
    const float* __restrict__ coords, const _Float16* __restrict__ coords_h,
    const float* __restrict__ sq, const float* __restrict__ feats,
    const float* __restrict__ Wo, const float* __restrict__ bo,
    float* __restrict__ out, int* __restrict__ flags)
{
  __shared__ unsigned cTh[TJ * HROW];             // 12288 B
  __shared__ float sqs[TJ];                       //  1024 B
  __shared__ unsigned short sbuf[QB][CAP];        //  6144 B
  __shared__ int scnt[QB];                        //    32 B
  __shared__ float featS[QB][64];                 //  2048 B
  __shared__ float aggS[QB][64];                  //  2048 B

  const int tid = threadIdx.x;       // 0..255
  const int lane = tid & 63;
  const int wave = tid >> 6;
  const int qbase = blockIdx.x * QB + wave * Q;

  if (tid < QB) scnt[tid] = 0;

  unsigned ciq[Q][8];
  float sqi[Q];
  #pragma unroll
  for (int q = 0; q < Q; ++q) {
    const uint4* cp = (const uint4*)(coords_h + (qbase + q) * 16);
    uint4 a = cp[0], b = cp[1];
    ciq[q][0] = a.x; ciq[q][1] = a.y; ciq[q][2] = a.z; ciq[q][3] = a.w;
    ciq[q][4] = b.x; ciq[q][5] = b.y; ciq[q][6] = b.z; ciq[q][7] = b.w;
    sqi[q] = sq[qbase + q];
  }

  // ===================== Phase A: per-lane approx min over sample ============
  float lmind[Q];
  #pragma unroll
  for (int q = 0; q < Q; ++q) lmind[q] = INFINITY;

  for (int tile = 0; tile < TAU_TILES; ++tile) {
    const int j0 = tile * TJ;
    __syncthreads();
    {
      const int j = j0 + tid;        // sample tiles: always in-range
      const uint4* cp = (const uint4*)(coords_h + j * 16);
      *(uint4*)&cTh[tid * HROW + 0] = cp[0];
      *(uint4*)&cTh[tid * HROW + 4] = cp[1];
      sqs[tid] = sq[j];
    }
    __syncthreads();

    #pragma unroll
    for (int h = 0; h < 4; ++h) {
      const int jl = h * 64 + lane;
      const int j = j0 + jl;
      const float sqj = sqs[jl];
      const uint4 u0 = *(const uint4*)&cTh[jl * HROW + 0];
      const uint4 u1 = *(const uint4*)&cTh[jl * HROW + 4];
      unsigned cj[8] = {u0.x, u0.y, u0.z, u0.w, u1.x, u1.y, u1.z, u1.w};
      #pragma unroll
      for (int q = 0; q < Q; ++q) {
        float dot = 0.0f;
        #pragma unroll
        for (int w = 0; w < 8; ++w)
          dot = __builtin_amdgcn_fdot2(__builtin_bit_cast(h2, ciq[q][w]),
                                       __builtin_bit_cast(h2, cj[w]), dot, false);
        float d2a = fmaf(-2.0f, dot, sqi[q] + sqj);
        if (j == qbase + q) d2a = INFINITY;
        lmind[q] = fminf(lmind[q], d2a);
      }
    }
  }

  // tau_q = 16th-smallest of the 64 lane minima (bitonic, take lane 15)
  float taug[Q];
  #pragma unroll
  for (int q = 0; q < Q; ++q) {
    float v = lmind[q];
    #pragma unroll
    for (int k = 2; k <= 64; k <<= 1) {
      #pragma unroll
      for (int s = k >> 1; s >= 1; s >>= 1) {
        const float o = __shfl_xor(v, s);
        const bool keepMin = (((lane & s) == 0) == ((lane & k) == 0));
        const float mn = fminf(v, o), mx = fmaxf(v, o);
        v = keepMin ? mn : mx;
      }
    }
    taug[q] = __shfl(v, 15) + MARGIN;   // sound gate
  }

  // ===================== Phase B: gated scan, push survivor indices ==========
  for (int tile = 0; tile < NTILES; ++tile) {
    const int j0 = tile * TJ;
    __syncthreads();
    {
      const int j = j0 + tid;
      uint4 a = make_uint4(0u,0u,0u,0u), b = a;
      float sv = 0.0f;
      if (j < N_PTS) {
        const uint4* cp = (const uint4*)(coords_h + j * 16);
        a = cp[0]; b = cp[1]; sv = sq[j];
      }
      *(uint4*)&cTh[tid * HROW + 0] = a;
      *(uint4*)&cTh[tid * HROW + 4] = b;
      sqs[tid] = sv;
    }
    __syncthreads();

    #pragma unroll
    for (int h = 0; h < 4; ++h) {
      const int jl = h * 64 + lane;
      const float sqj = sqs[jl];
      const uint4 u0 = *(const uint4*)&cTh[jl * HROW + 0];
      const uint4 u1 = *(const uint4*)&cTh[jl * HROW + 4];
      unsigned cj[8] = {u0.x, u0.y, u0.z, u0.w, u1.x, u1.y, u1.z, u1.w};
      #pragma unroll
      for (int q = 0; q < Q; ++q) {
        float dot = 0.0f;
        #pragma unroll
        for (int w = 0; w < 8; ++w)
          dot = __builtin_amdgcn_fdot2(__builtin_bit_cast(h2, ciq[q][w]),
                                       __builtin_bit_cast(h2, cj[w]), dot, false);
        const float d2a = fmaf(-2.0f, dot, sqi[q] + sqj);
        if (d2a <= taug[q]) {            // self/pad pass; filtered in Phase C
          const int wq = wave * Q + q;
          const int p = atomicAdd(&scnt[wq], 1);
          if (p < CAP) sbuf[wq][p] = (unsigned short)(j0 + jl);
        }
      }
    }
  }

  // ===================== Phase C: exact fp32 re-score + top-16 ===============
  #pragma unroll
  for (int q = 0; q < Q; ++q) {
    const int wq = wave * Q + q;
    const int cq = scnt[wq];             // own-wave LDS ops: ordered
    const int nread = (cq < CAP) ? cq : CAP;

    float ci[16];
    {
      const float4* cp = (const float4*)(coords + (qbase + q) * 16);
      *(float4*)&ci[0] = cp[0]; *(float4*)&ci[4] = cp[1];
      *(float4*)&ci[8] = cp[2]; *(float4*)&ci[12] = cp[3];
    }

    u64 k6[6];
    #pragma unroll
    for (int t = 0; t < 6; ++t) k6[t] = ((u64)(0x7F000000u + t) << 32);
    u64 kmax6 = ((u64)0x7F000005u << 32);

    #pragma unroll
    for (int t = 0; t < CAP / 64; ++t) { // <=6 offers/lane: no eviction
      const int idx = t * 64 + lane;
      u64 key = ~0ull;
      if (idx < nread) {
        const int jj = sbuf[wq][idx];
        if (jj < N_PTS && jj != qbase + q) {
          const float4* cp = (const float4*)(coords + jj * 16);
          float cj[16];
          *(float4*)&cj[0]  = cp[0]; *(float4*)&cj[4]  = cp[1];
          *(float4*)&cj[8]  = cp[2]; *(float4*)&cj[12] = cp[3];
          float dot = 0.0f;
          #pragma unroll
          for (int d = 0; d < 16; ++d) dot = fmaf(ci[d], cj[d], dot);
          const float d2 = fmaxf(fmaf(-2.0f, dot, sqi[q] + sq[jj]), 0.0f);
          key = ((u64)__float_as_uint(d2) << 32) | (unsigned)jj;
        }
      }
      ins6(key, k6, kmax6);
    }

    u64 lmin = k6[0];
    #pragma unroll
    for (int t = 1; t < 6; ++t) lmin = (k6[t] < lmin) ? k6[t] : lmin;

    float aggv = 0.0f;
    for (int r = 0; r < KNN; ++r) {
      const u64 m = minbfly(lmin);
      if (lmin == m) {
        #pragma unroll
        for (int t = 0; t < 6; ++t) k6[t] = (k6[t] == m) ? ~0ull : k6[t];
        lmin = k6[0];
        #pragma unroll
        for (int t = 1; t < 6; ++t) lmin = (k6[t] < lmin) ? k6[t] : lmin;
      }
      const unsigned hi = (unsigned)(m >> 32);
      const bool ok = hi < 0x7F000000u;
      const float w = ok ? expf(-__uint_as_float(hi)) : 0.0f;
      const int jj = ok ? (int)(unsigned)(m & 0xFFFFFFFFull) : 0;
      aggv = fmaf(w, feats[jj * 64 + lane], aggv);
    }
    aggS[wq][lane] = aggv;
    featS[wq][lane] = feats[(qbase + q) * 64 + lane];
    if (lane == 0) flags[qbase + q] = (cq > CAP);
  }

  // ===================== Epilogue: fused out GEMM (8 rows/block) =============
  __syncthreads();
  const int row = tid >> 5;        // 0..7
  const int c0 = tid & 31;         // cols c0 and c0+32
  float acc0 = bo[c0], acc1 = bo[c0 + 32];
  #pragma unroll
  for (int f = 0; f < 64; ++f) {
    const float fv = featS[row][f];
    const float av = aggS[row][f];
    acc0 = fmaf(fv, Wo[f * 64 + c0],        acc0);
    acc1 = fmaf(fv, Wo[f * 64 + c0 + 32],   acc1);
    acc0 = fmaf(av, Wo[(64 + f) * 64 + c0],      acc0);
    acc1 = fmaf(av, Wo[(64 + f) * 64 + c0 + 32], acc1);
  }
  const int orow = blockIdx.x * QB + row;
  out[orow * 64 + c0]      = acc0;
  out[orow * 64 + c0 + 32] = acc1;
}

// ---------------------------------------------------------------------------
// Kernel 2b: exact fallback for flagged (overflowed) queries — expected zero.
// Recomputes the full row: exact KNN + aggregation + fused out row.
// ---------------------------------------------------------------------------
__global__ __launch_bounds__(256) void knn_fixup_kernel(
    const float* __restrict__ coords, const float* __restrict__ sq,
    const float* __restrict__ feats, const int* __restrict__ flags,
    const float* __restrict__ Wo, const float* __restrict__ bo,
    float* __restrict__ out)
{
  const int wave = threadIdx.x >> 6;
  const int lane = threadIdx.x & 63;
  const int i = blockIdx.x * 4 + wave;
  if (i >= N_PTS) return;
  if (!flags[i]) return;
  float ci[16];
  #pragma unroll
  for (int d = 0; d < 16; ++d) ci[d] = coords[i * 16 + d];
  const float sqi = sq[i];

  u64 k8a[8], k8b[8], kmaxA, kmaxB;
  #pragma unroll
  for (int t = 0; t < 8; ++t) {
    k8a[t] = ((u64)(0x7F000000u + t) << 32);
    k8b[t] = ((u64)(0x7F000000u + t) << 32);
  }
  kmaxA = ((u64)0x7F000007u << 32);
  kmaxB = ((u64)0x7F000007u << 32);

  const int niter = (N_PTS + 63) / 64;  // 188
  for (int t = 0; t < niter; ++t) {
    const int j = t * 64 + lane;
    float4 c0 = make_float4(0,0,0,0), c1 = c0, c2 = c0, c3 = c0;
    float sqj = 0.0f;
    if (j < N_PTS) {
      const float4* cp = (const float4*)(coords + j * 16);
      c0 = cp[0]; c1 = cp[1]; c2 = cp[2]; c3 = cp[3];
      sqj = sq[j];
    }
    float dot = ci[0]*c0.x + ci[1]*c0.y + ci[2]*c0.z + ci[3]*c0.w
              + ci[4]*c1.x + ci[5]*c1.y + ci[6]*c1.z + ci[7]*c1.w
              + ci[8]*c2.x + ci[9]*c2.y + ci[10]*c2.z + ci[11]*c2.w
              + ci[12]*c3.x + ci[13]*c3.y + ci[14]*c3.z + ci[15]*c3.w;
    float d2 = fmaxf(fmaf(-2.0f, dot, sqi + sqj), 0.0f);
    const unsigned hi = (j == i || j >= N_PTS) ? 0xFFFFFFFFu : __float_as_uint(d2);
    const u64 key = ((u64)hi << 32) | (unsigned)j;
    if (t & 1) ins8(key, k8a, kmaxA);
    else       ins8(key, k8b, kmaxB);
  }

  u64 tab[16];
  #pragma unroll
  for (int t = 0; t < 8; ++t) { tab[t] = k8a[t]; tab[8 + t] = k8b[t]; }
  u64 lmin = tab[0];
  #pragma unroll
  for (int t = 1; t < 16; ++t) lmin = (tab[t] < lmin) ? tab[t] : lmin;

  float aggv = 0.0f;
  u64 T16 = 0;
  for (int r = 0; r < KNN; ++r) {
    const u64 m = minbfly(lmin);
    if (lmin == m) {
      #pragma unroll
      for (int t = 0; t < 16; ++t) tab[t] = (tab[t] == m) ? ~0ull : tab[t];
      lmin = tab[0];
      #pragma unroll
      for (int t = 1; t < 16; ++t) lmin = (tab[t] < lmin) ? tab[t] : lmin;
    }
    const unsigned hi = (unsigned)(m >> 32);
    const bool ok = hi < 0x7F000000u;
    const float w = ok ? expf(-__uint_as_float(hi)) : 0.0f;
    const int jj = ok ? (int)(unsigned)(m & 0xFFFFFFFFull) : 0;
    aggv = fmaf(w, feats[jj * 64 + lane], aggv);
    T16 = m;
  }

  if (__any((kmaxA < T16) || (kmaxB < T16))) {
    aggv = 0.0f;
    u64 prev = 0;
    for (int r = 0; r < KNN; ++r) {
      u64 best = ~0ull;
      for (int j = lane; j < N_PTS; j += 64) {
        float dot = 0.0f;
        #pragma unroll
        for (int d = 0; d < 16; ++d) dot = fmaf(ci[d], coords[j * 16 + d], dot);
        const float d2 = fmaxf(fmaf(-2.0f, dot, sqi + sq[j]), 0.0f);
        const unsigned hi = (j == i) ? 0xFFFFFFFFu : __float_as_uint(d2);
        const u64 key = ((u64)hi << 32) | (unsigned)j;
        const bool cand = (r == 0) || (key > prev);
        if (cand && key < best) best = key;
      }
      const u64 m = minbfly(best);
      prev = m;
      const unsigned hi = (unsigned)(m >> 32);
      const bool ok = hi < 0x7F000000u;
      const float w = ok ? expf(-__uint_as_float(hi)) : 0.0f;
      const int jj = ok ? (int)(unsigned)(m & 0xFFFFFFFFull) : 0;
      aggv = fmaf(w, feats[jj * 64 + lane], aggv);
    }
  }

  // fused output row
  const float fl = feats[i * 64 + lane];
  float acc = bo[lane];
  #pragma unroll
  for (int f = 0; f < 64; ++f) {
    acc = fmaf(__shfl(fl, f),   Wo[f * 64 + lane],        acc);
    acc = fmaf(__shfl(aggv, f), Wo[(64 + f) * 64 + lane], acc);
  }
  out[i * 64 + lane] = acc;
}

extern "C" void kernel_launch(void* const* d_in, const int* in_sizes, int n_in,
                              void* d_out, int out_size, void* d_ws, size_t ws_size,
                              hipStream_t stream) {
  const float* x  = (const float*)d_in[0];
  const float* Wf = (const float*)d_in[1];
  const float* bf = (const float*)d_in[2];
  const float* Wl = (const float*)d_in[3];
  const float* bl = (const float*)d_in[4];
  const float* Wo = (const float*)d_in[5];
  const float* bo = (const float*)d_in[6];
  float* out = (float*)d_out;

  char* ws = (char*)d_ws;
  float*     feats    = (float*)(ws);                 // 3,072,000 B
  float*     coords   = (float*)(ws + 3072000);       //   768,000 B
  float*     sqv      = (float*)(ws + 3840000);       //    48,000 B
  _Float16*  coords_h = (_Float16*)(ws + 3888000);    //   384,000 B
  int*       flags    = (int*)(ws + 4272000);         //    48,000 B

  encoder_kernel<<<3000, 256, 0, stream>>>(x, Wf, bf, Wl, bl, feats, coords, coords_h, sqv);
  knn_agg_kernel<<<N_PTS / QB, 256, 0, stream>>>(coords, coords_h, sqv, feats, Wo, bo, out, flags);
  knn_fixup_kernel<<<3000, 256, 0, stream>>>(coords, sqv, feats, flags, Wo, bo, out);
}

// Round 13
// 312.700 us; speedup vs baseline: 1.1002x; 1.1002x over previous
//
#include <hip/hip_runtime.h>
#include <math.h>

typedef unsigned long long u64;
typedef _Float16 h2 __attribute__((ext_vector_type(2)));

#define N_PTS 12000
#define KNN 16
#define Q 4        // queries per wave
#define WPB 2      // waves per block (128-thread blocks)
#define QB (WPB * Q)                     // 8 queries per block
#define NB_ITER ((N_PTS + 63) / 64)      // 188 scan iterations
#define TAU_PTS 2048                     // sample size
#define TAU_ITER (TAU_PTS / 64)          // 32
#define CAP 384                          // survivor capacity; 6 offers/lane
#define MARGIN 0.08f                     // > 2*m, m = f16 d2 error bound ~0.032

// ---------------------------------------------------------------------------
// Kernel 1: encoders. feats = tanh(x@Wf+bf); coords = tanh(x@Wl+bl) fp32+f16;
// sq = |coords|^2. One wave per row.
// ---------------------------------------------------------------------------
__global__ __launch_bounds__(256) void encoder_kernel(
    const float* __restrict__ x, const float* __restrict__ Wf, const float* __restrict__ bf,
    const float* __restrict__ Wl, const float* __restrict__ bl,
    float* __restrict__ feats, float* __restrict__ coords, _Float16* __restrict__ coords_h,
    float* __restrict__ sq)
{
  const int wave = threadIdx.x >> 6;
  const int lane = threadIdx.x & 63;
  const int i = blockIdx.x * 4 + wave;
  if (i >= N_PTS) return;
  float xv = x[i * 64 + lane];
  float accf = bf[lane];
  float accc = bl[lane & 15];
  #pragma unroll
  for (int k = 0; k < 64; ++k) {
    float xk = __shfl(xv, k);
    accf = fmaf(xk, Wf[k * 64 + lane], accf);
    accc = fmaf(xk, Wl[k * 16 + (lane & 15)], accc);
  }
  feats[i * 64 + lane] = tanhf(accf);
  float c = tanhf(accc);
  float cc = (lane < 16) ? c * c : 0.0f;
  cc += __shfl_xor(cc, 1);
  cc += __shfl_xor(cc, 2);
  cc += __shfl_xor(cc, 4);
  cc += __shfl_xor(cc, 8);
  if (lane < 16) {
    coords[i * 16 + lane] = c;
    coords_h[i * 16 + lane] = (_Float16)c;
  }
  if (lane == 0) sq[i] = cc;
}

// ---------------------------------------------------------------------------
// u64-key helpers. Keys (f32bits(d2)<<32)|j unique; sentinels (0x7F00000t<<32)
// exceed any real key; ~0ull matches no slot.
// ---------------------------------------------------------------------------
__device__ __forceinline__ void ins6(u64 key, u64* k6, u64& kmax) {
  const u64 om = (key < kmax) ? kmax : ~0ull;
  #pragma unroll
  for (int t = 0; t < 6; ++t)
    k6[t] = (k6[t] == om) ? key : k6[t];
  u64 a = k6[0] > k6[1] ? k6[0] : k6[1];
  u64 b = k6[2] > k6[3] ? k6[2] : k6[3];
  u64 c = k6[4] > k6[5] ? k6[4] : k6[5];
  a = a > b ? a : b;
  kmax = a > c ? a : c;
}

__device__ __forceinline__ void ins8(u64 key, u64* k8, u64& kmax) {
  const u64 om = (key < kmax) ? kmax : ~0ull;
  #pragma unroll
  for (int t = 0; t < 8; ++t)
    k8[t] = (k8[t] == om) ? key : k8[t];
  u64 a = k8[0] > k8[1] ? k8[0] : k8[1];
  u64 b = k8[2] > k8[3] ? k8[2] : k8[3];
  u64 c = k8[4] > k8[5] ? k8[4] : k8[5];
  u64 d = k8[6] > k8[7] ? k8[6] : k8[7];
  a = a > b ? a : b;
  c = c > d ? c : d;
  kmax = a > c ? a : c;
}

__device__ __forceinline__ u64 shflx_u64(u64 v, int off) {
  int lo = __shfl_xor((int)(unsigned)v, off);
  int hi = __shfl_xor((int)(unsigned)(v >> 32), off);
  return ((u64)(unsigned)hi << 32) | (unsigned)lo;
}

__device__ __forceinline__ u64 minbfly(u64 m) {
  #pragma unroll
  for (int off = 32; off >= 1; off >>= 1) {
    u64 o = shflx_u64(m, off);
    m = (o < m) ? o : m;
  }
  return m;
}

// ---------------------------------------------------------------------------
// Kernel 2: KNN + gaussian aggregation. Wave = 4 queries, block = 2 waves.
// NO LDS candidate staging, NO barriers: coords_h (384 KB) is L2-resident,
// lanes read candidates with coalesced 32 B global loads; 188 independent
// iterations pipeline freely (R10's barrier+vmcnt(0) drain was ~70% of its
// runtime at 2.93 waves/SIMD; this removes the barrier structure entirely).
// Phase A (f16 fdot2): per-lane min over 2048-pt sample; tau = 16th order
//   stat of lane minima + MARGIN (sound: exact-16th <= tau_a + m, so every
//   true member's approx d2 <= tau_a + 2m < gate).
// Phase B (f16 fdot2): full scan; approx d2 <= gate pushes u16 index into
//   own-wave LDS survivor buffer (self/pad filtered in C).
// Phase C: exact fp32 re-score (reference-identical fmaf chain), exact
//   top-16 via 6-slot tables (<=6 offers/lane: no eviction) + minbfly.
// Only failure mode: survivor overflow -> flag -> fixup kernel.
// ---------------------------------------------------------------------------
__global__ __launch_bounds__(128) void knn_agg_kernel(
    const float* __restrict__ coords, const _Float16* __restrict__ coords_h,
    const float* __restrict__ sq, const float* __restrict__ feats,
    float* __restrict__ agg, int* __restrict__ flags)
{
  __shared__ unsigned short sbuf[QB][CAP];   // 6144 B
  __shared__ int scnt[QB];                   //   32 B

  const int tid = threadIdx.x;       // 0..127
  const int lane = tid & 63;
  const int wave = tid >> 6;
  const int qbase = blockIdx.x * QB + wave * Q;

  if (tid < QB) scnt[tid] = 0;
  // no barrier needed: scnt[wq]/sbuf[wq] are touched only by wave wq>>1 = wave
  // (each wave zeroes its own entries: tid<QB covers wq 0..7; wave0 zeroes 0..7
  //  -- wave 1's counters zeroed by wave 0! Need a barrier once at start.)
  __syncthreads();

  unsigned ciq[Q][8];
  float sqi[Q];
  #pragma unroll
  for (int q = 0; q < Q; ++q) {
    const uint4* cp = (const uint4*)(coords_h + (qbase + q) * 16);
    uint4 a = cp[0], b = cp[1];
    ciq[q][0] = a.x; ciq[q][1] = a.y; ciq[q][2] = a.z; ciq[q][3] = a.w;
    ciq[q][4] = b.x; ciq[q][5] = b.y; ciq[q][6] = b.z; ciq[q][7] = b.w;
    sqi[q] = sq[qbase + q];
  }

  // ===================== Phase A: per-lane approx min over sample ============
  float lmind[Q];
  #pragma unroll
  for (int q = 0; q < Q; ++q) lmind[q] = INFINITY;

  for (int t = 0; t < TAU_ITER; ++t) {
    const int j = t * 64 + lane;               // < 2048: always in-range
    const uint4* cp = (const uint4*)(coords_h + j * 16);
    const uint4 u0 = cp[0];
    const uint4 u1 = cp[1];
    const float sqj = sq[j];
    unsigned cj[8] = {u0.x, u0.y, u0.z, u0.w, u1.x, u1.y, u1.z, u1.w};
    #pragma unroll
    for (int q = 0; q < Q; ++q) {
      float dot = 0.0f;
      #pragma unroll
      for (int w = 0; w < 8; ++w)
        dot = __builtin_amdgcn_fdot2(__builtin_bit_cast(h2, ciq[q][w]),
                                     __builtin_bit_cast(h2, cj[w]), dot, false);
      float d2a = fmaf(-2.0f, dot, sqi[q] + sqj);
      if (j == qbase + q) d2a = INFINITY;
      lmind[q] = fminf(lmind[q], d2a);
    }
  }

  // tau_q = 16th-smallest of the 64 lane minima (bitonic, take lane 15)
  float taug[Q];
  #pragma unroll
  for (int q = 0; q < Q; ++q) {
    float v = lmind[q];
    #pragma unroll
    for (int k = 2; k <= 64; k <<= 1) {
      #pragma unroll
      for (int s = k >> 1; s >= 1; s >>= 1) {
        const float o = __shfl_xor(v, s);
        const bool keepMin = (((lane & s) == 0) == ((lane & k) == 0));
        const float mn = fminf(v, o), mx = fmaxf(v, o);
        v = keepMin ? mn : mx;
      }
    }
    taug[q] = __shfl(v, 15) + MARGIN;   // sound gate
  }

  // ===================== Phase B: gated scan, push survivor indices ==========
  for (int t = 0; t < NB_ITER; ++t) {
    const int j = t * 64 + lane;
    uint4 u0 = make_uint4(0u,0u,0u,0u), u1 = u0;
    float sqj = 0.0f;
    bool inr = (j < N_PTS);
    if (inr) {
      const uint4* cp = (const uint4*)(coords_h + j * 16);
      u0 = cp[0]; u1 = cp[1]; sqj = sq[j];
    }
    unsigned cj[8] = {u0.x, u0.y, u0.z, u0.w, u1.x, u1.y, u1.z, u1.w};
    #pragma unroll
    for (int q = 0; q < Q; ++q) {
      float dot = 0.0f;
      #pragma unroll
      for (int w = 0; w < 8; ++w)
        dot = __builtin_amdgcn_fdot2(__builtin_bit_cast(h2, ciq[q][w]),
                                     __builtin_bit_cast(h2, cj[w]), dot, false);
      float d2a = fmaf(-2.0f, dot, sqi[q] + sqj);
      if (!inr) d2a = INFINITY;
      if (d2a <= taug[q]) {              // self passes; filtered in Phase C
        const int wq = wave * Q + q;
        const int p = atomicAdd(&scnt[wq], 1);
        if (p < CAP) sbuf[wq][p] = (unsigned short)j;
      }
    }
  }

  // ===================== Phase C: exact fp32 re-score + top-16 ===============
  #pragma unroll
  for (int q = 0; q < Q; ++q) {
    const int wq = wave * Q + q;
    const int cq = scnt[wq];             // own-wave LDS ops: ordered
    const int nread = (cq < CAP) ? cq : CAP;

    float ci[16];
    {
      const float4* cp = (const float4*)(coords + (qbase + q) * 16);
      *(float4*)&ci[0] = cp[0]; *(float4*)&ci[4] = cp[1];
      *(float4*)&ci[8] = cp[2]; *(float4*)&ci[12] = cp[3];
    }

    u64 k6[6];
    #pragma unroll
    for (int t = 0; t < 6; ++t) k6[t] = ((u64)(0x7F000000u + t) << 32);
    u64 kmax6 = ((u64)0x7F000005u << 32);

    #pragma unroll
    for (int t = 0; t < CAP / 64; ++t) { // <=6 offers/lane: no eviction
      const int idx = t * 64 + lane;
      u64 key = ~0ull;
      if (idx < nread) {
        const int jj = sbuf[wq][idx];
        if (jj != qbase + q) {
          const float4* cp = (const float4*)(coords + jj * 16);
          float cj[16];
          *(float4*)&cj[0]  = cp[0]; *(float4*)&cj[4]  = cp[1];
          *(float4*)&cj[8]  = cp[2]; *(float4*)&cj[12] = cp[3];
          float dot = 0.0f;
          #pragma unroll
          for (int d = 0; d < 16; ++d) dot = fmaf(ci[d], cj[d], dot);
          const float d2 = fmaxf(fmaf(-2.0f, dot, sqi[q] + sq[jj]), 0.0f);
          key = ((u64)__float_as_uint(d2) << 32) | (unsigned)jj;
        }
      }
      ins6(key, k6, kmax6);
    }

    u64 lmin = k6[0];
    #pragma unroll
    for (int t = 1; t < 6; ++t) lmin = (k6[t] < lmin) ? k6[t] : lmin;

    float aggv = 0.0f;
    for (int r = 0; r < KNN; ++r) {
      const u64 m = minbfly(lmin);
      if (lmin == m) {
        #pragma unroll
        for (int t = 0; t < 6; ++t) k6[t] = (k6[t] == m) ? ~0ull : k6[t];
        lmin = k6[0];
        #pragma unroll
        for (int t = 1; t < 6; ++t) lmin = (k6[t] < lmin) ? k6[t] : lmin;
      }
      const unsigned hi = (unsigned)(m >> 32);
      const bool ok = hi < 0x7F000000u;
      const float w = ok ? expf(-__uint_as_float(hi)) : 0.0f;
      const int jj = ok ? (int)(unsigned)(m & 0xFFFFFFFFull) : 0;
      aggv = fmaf(w, feats[jj * 64 + lane], aggv);
    }
    agg[(qbase + q) * 64 + lane] = aggv;
    if (lane == 0) flags[qbase + q] = (cq > CAP);
  }
}

// ---------------------------------------------------------------------------
// Kernel 2b: exact fallback for flagged (overflowed) queries — expected zero.
// ---------------------------------------------------------------------------
__global__ __launch_bounds__(256) void knn_fixup_kernel(
    const float* __restrict__ coords, const float* __restrict__ sq,
    const float* __restrict__ feats, const int* __restrict__ flags,
    float* __restrict__ agg)
{
  const int wave = threadIdx.x >> 6;
  const int lane = threadIdx.x & 63;
  const int i = blockIdx.x * 4 + wave;
  if (i >= N_PTS) return;
  if (!flags[i]) return;
  float ci[16];
  #pragma unroll
  for (int d = 0; d < 16; ++d) ci[d] = coords[i * 16 + d];
  const float sqi = sq[i];

  u64 k8a[8], k8b[8], kmaxA, kmaxB;
  #pragma unroll
  for (int t = 0; t < 8; ++t) {
    k8a[t] = ((u64)(0x7F000000u + t) << 32);
    k8b[t] = ((u64)(0x7F000000u + t) << 32);
  }
  kmaxA = ((u64)0x7F000007u << 32);
  kmaxB = ((u64)0x7F000007u << 32);

  const int niter = (N_PTS + 63) / 64;  // 188
  for (int t = 0; t < niter; ++t) {
    const int j = t * 64 + lane;
    float4 c0 = make_float4(0,0,0,0), c1 = c0, c2 = c0, c3 = c0;
    float sqj = 0.0f;
    if (j < N_PTS) {
      const float4* cp = (const float4*)(coords + j * 16);
      c0 = cp[0]; c1 = cp[1]; c2 = cp[2]; c3 = cp[3];
      sqj = sq[j];
    }
    float dot = ci[0]*c0.x + ci[1]*c0.y + ci[2]*c0.z + ci[3]*c0.w
              + ci[4]*c1.x + ci[5]*c1.y + ci[6]*c1.z + ci[7]*c1.w
              + ci[8]*c2.x + ci[9]*c2.y + ci[10]*c2.z + ci[11]*c2.w
              + ci[12]*c3.x + ci[13]*c3.y + ci[14]*c3.z + ci[15]*c3.w;
    float d2 = fmaxf(fmaf(-2.0f, dot, sqi + sqj), 0.0f);
    const unsigned hi = (j == i || j >= N_PTS) ? 0xFFFFFFFFu : __float_as_uint(d2);
    const u64 key = ((u64)hi << 32) | (unsigned)j;
    if (t & 1) ins8(key, k8a, kmaxA);
    else       ins8(key, k8b, kmaxB);
  }

  u64 tab[16];
  #pragma unroll
  for (int t = 0; t < 8; ++t) { tab[t] = k8a[t]; tab[8 + t] = k8b[t]; }
  u64 lmin = tab[0];
  #pragma unroll
  for (int t = 1; t < 16; ++t) lmin = (tab[t] < lmin) ? tab[t] : lmin;

  float aggv = 0.0f;
  u64 T16 = 0;
  for (int r = 0; r < KNN; ++r) {
    const u64 m = minbfly(lmin);
    if (lmin == m) {
      #pragma unroll
      for (int t = 0; t < 16; ++t) tab[t] = (tab[t] == m) ? ~0ull : tab[t];
      lmin = tab[0];
      #pragma unroll
      for (int t = 1; t < 16; ++t) lmin = (tab[t] < lmin) ? tab[t] : lmin;
    }
    const unsigned hi = (unsigned)(m >> 32);
    const bool ok = hi < 0x7F000000u;
    const float w = ok ? expf(-__uint_as_float(hi)) : 0.0f;
    const int jj = ok ? (int)(unsigned)(m & 0xFFFFFFFFull) : 0;
    aggv = fmaf(w, feats[jj * 64 + lane], aggv);
    T16 = m;
  }

  if (__any((kmaxA < T16) || (kmaxB < T16))) {
    aggv = 0.0f;
    u64 prev = 0;
    for (int r = 0; r < KNN; ++r) {
      u64 best = ~0ull;
      for (int j = lane; j < N_PTS; j += 64) {
        float dot = 0.0f;
        #pragma unroll
        for (int d = 0; d < 16; ++d) dot = fmaf(ci[d], coords[j * 16 + d], dot);
        const float d2 = fmaxf(fmaf(-2.0f, dot, sqi + sq[j]), 0.0f);
        const unsigned hi = (j == i) ? 0xFFFFFFFFu : __float_as_uint(d2);
        const u64 key = ((u64)hi << 32) | (unsigned)j;
        const bool cand = (r == 0) || (key > prev);
        if (cand && key < best) best = key;
      }
      const u64 m = minbfly(best);
      prev = m;
      const unsigned hi = (unsigned)(m >> 32);
      const bool ok = hi < 0x7F000000u;
      const float w = ok ? expf(-__uint_as_float(hi)) : 0.0f;
      const int jj = ok ? (int)(unsigned)(m & 0xFFFFFFFFull) : 0;
      aggv = fmaf(w, feats[jj * 64 + lane], aggv);
    }
  }
  agg[i * 64 + lane] = aggv;
}

// ---------------------------------------------------------------------------
// Kernel 3: out = concat(feats, agg) @ W_out + b_out. Two rows per thread
// share the Wo loads.
// ---------------------------------------------------------------------------
__global__ __launch_bounds__(256) void out_kernel(
    const float* __restrict__ feats, const float* __restrict__ agg,
    const float* __restrict__ Wo, const float* __restrict__ bo,
    float* __restrict__ out)
{
  const int idx = blockIdx.x * 256 + threadIdx.x;
  const int pr = idx >> 6, o = idx & 63;
  const int i0 = pr * 2;
  if (i0 >= N_PTS) return;
  float acc0 = bo[o], acc1 = acc0;
  #pragma unroll
  for (int f = 0; f < 64; ++f) {
    const float w1 = Wo[f * 64 + o];
    acc0 = fmaf(feats[i0 * 64 + f], w1, acc0);
    acc1 = fmaf(feats[(i0 + 1) * 64 + f], w1, acc1);
  }
  #pragma unroll
  for (int f = 0; f < 64; ++f) {
    const float w2 = Wo[(64 + f) * 64 + o];
    acc0 = fmaf(agg[i0 * 64 + f], w2, acc0);
    acc1 = fmaf(agg[(i0 + 1) * 64 + f], w2, acc1);
  }
  out[i0 * 64 + o] = acc0;
  out[(i0 + 1) * 64 + o] = acc1;
}

extern "C" void kernel_launch(void* const* d_in, const int* in_sizes, int n_in,
                              void* d_out, int out_size, void* d_ws, size_t ws_size,
                              hipStream_t stream) {
  const float* x  = (const float*)d_in[0];
  const float* Wf = (const float*)d_in[1];
  const float* bf = (const float*)d_in[2];
  const float* Wl = (const float*)d_in[3];
  const float* bl = (const float*)d_in[4];
  const float* Wo = (const float*)d_in[5];
  const float* bo = (const float*)d_in[6];
  float* out = (float*)d_out;

  char* ws = (char*)d_ws;
  float*     feats    = (float*)(ws);                 // 3,072,000 B
  float*     coords   = (float*)(ws + 3072000);       //   768,000 B
  float*     sqv      = (float*)(ws + 3840000);       //    48,000 B
  _Float16*  coords_h = (_Float16*)(ws + 3888000);    //   384,000 B
  float*     agg      = (float*)(ws + 4272000);       // 3,072,000 B
  int*       flags    = (int*)(ws + 7344000);         //    48,000 B

  encoder_kernel<<<3000, 256, 0, stream>>>(x, Wf, bf, Wl, bl, feats, coords, coords_h, sqv);
  knn_agg_kernel<<<N_PTS / QB, 128, 0, stream>>>(coords, coords_h, sqv, feats, agg, flags);
  knn_fixup_kernel<<<3000, 256, 0, stream>>>(coords, sqv, feats, flags, agg);
  out_kernel<<<1500, 256, 0, stream>>>(feats, agg, Wo, bo, out);
}

// Round 14
// 207.201 us; speedup vs baseline: 1.6603x; 1.5092x over previous
//
#include <hip/hip_runtime.h>
#include <math.h>

typedef unsigned long long u64;
typedef _Float16 f16x8 __attribute__((ext_vector_type(8)));
typedef float f32x4 __attribute__((ext_vector_type(4)));

#define N_PTS 12000
#define KNN 16
#define QB 16                            // queries per block (MFMA M dim)
#define NWAVES 8                         // waves per block (512 threads)
#define NGROUPS (N_PTS / 16)             // 750 candidate groups of 16
#define TAU_PTS 2048
#define TAU_GROUPS (TAU_PTS / 16)        // 128
#define CAP 384                          // survivor capacity; 6 offers/lane
#define MARGIN 0.08f                     // > 2*m, m = f16 d2 error bound ~0.032

// ---------------------------------------------------------------------------
// Kernel 1: encoders. feats = tanh(x@Wf+bf); coords = tanh(x@Wl+bl) fp32+f16;
// sq = |coords|^2. One wave per row.
// ---------------------------------------------------------------------------
__global__ __launch_bounds__(256) void encoder_kernel(
    const float* __restrict__ x, const float* __restrict__ Wf, const float* __restrict__ bf,
    const float* __restrict__ Wl, const float* __restrict__ bl,
    float* __restrict__ feats, float* __restrict__ coords, _Float16* __restrict__ coords_h,
    float* __restrict__ sq)
{
  const int wave = threadIdx.x >> 6;
  const int lane = threadIdx.x & 63;
  const int i = blockIdx.x * 4 + wave;
  if (i >= N_PTS) return;
  float xv = x[i * 64 + lane];
  float accf = bf[lane];
  float accc = bl[lane & 15];
  #pragma unroll
  for (int k = 0; k < 64; ++k) {
    float xk = __shfl(xv, k);
    accf = fmaf(xk, Wf[k * 64 + lane], accf);
    accc = fmaf(xk, Wl[k * 16 + (lane & 15)], accc);
  }
  feats[i * 64 + lane] = tanhf(accf);
  float c = tanhf(accc);
  float cc = (lane < 16) ? c * c : 0.0f;
  cc += __shfl_xor(cc, 1);
  cc += __shfl_xor(cc, 2);
  cc += __shfl_xor(cc, 4);
  cc += __shfl_xor(cc, 8);
  if (lane < 16) {
    coords[i * 16 + lane] = c;
    coords_h[i * 16 + lane] = (_Float16)c;
  }
  if (lane == 0) sq[i] = cc;
}

// ---------------------------------------------------------------------------
// u64-key helpers. Keys (f32bits(d2)<<32)|j unique; sentinels (0x7F00000t<<32)
// exceed any real key; ~0ull matches no slot.
// ---------------------------------------------------------------------------
__device__ __forceinline__ void ins6(u64 key, u64* k6, u64& kmax) {
  const u64 om = (key < kmax) ? kmax : ~0ull;
  #pragma unroll
  for (int t = 0; t < 6; ++t)
    k6[t] = (k6[t] == om) ? key : k6[t];
  u64 a = k6[0] > k6[1] ? k6[0] : k6[1];
  u64 b = k6[2] > k6[3] ? k6[2] : k6[3];
  u64 c = k6[4] > k6[5] ? k6[4] : k6[5];
  a = a > b ? a : b;
  kmax = a > c ? a : c;
}

__device__ __forceinline__ void ins8(u64 key, u64* k8, u64& kmax) {
  const u64 om = (key < kmax) ? kmax : ~0ull;
  #pragma unroll
  for (int t = 0; t < 8; ++t)
    k8[t] = (k8[t] == om) ? key : k8[t];
  u64 a = k8[0] > k8[1] ? k8[0] : k8[1];
  u64 b = k8[2] > k8[3] ? k8[2] : k8[3];
  u64 c = k8[4] > k8[5] ? k8[4] : k8[5];
  u64 d = k8[6] > k8[7] ? k8[6] : k8[7];
  a = a > b ? a : b;
  c = c > d ? c : d;
  kmax = a > c ? a : c;
}

__device__ __forceinline__ u64 shflx_u64(u64 v, int off) {
  int lo = __shfl_xor((int)(unsigned)v, off);
  int hi = __shfl_xor((int)(unsigned)(v >> 32), off);
  return ((u64)(unsigned)hi << 32) | (unsigned)lo;
}

__device__ __forceinline__ u64 minbfly(u64 m) {
  #pragma unroll
  for (int off = 32; off >= 1; off >>= 1) {
    u64 o = shflx_u64(m, off);
    m = (o < m) ? o : m;
  }
  return m;
}

// ---------------------------------------------------------------------------
// Kernel 2: MFMA-based KNN + gaussian aggregation.
// Block = 16 queries, 8 waves. A-frag = 16 queries f16 coords (K=16 in a
// K=32 MFMA, upper half zero). Per 16-cand group: one coalesced B-frag load
// + one mfma_f32_16x16x32_f16 -> 256 dots. C layout (m89-verified):
// col=lane&15 (candidate), row=(lane>>4)*4+reg (query).
// Phase A: per-(row,col) running min over 2048-pt sample (self->INF); 128
//   disjoint column minima per query -> pairwise-min to 64 -> 16th order
//   stat (bitonic) + MARGIN = sound gate (identical bound chain as before).
// Phase B: full scan, gate, push u16 index into per-query block sbuf.
// Phase C: exact fp32 re-score + 6-slot tables + minbfly (exact; <=6
//   offers/lane). Only failure mode: overflow -> flag -> fixup.
// ---------------------------------------------------------------------------
__global__ __launch_bounds__(512) void knn_agg_kernel(
    const float* __restrict__ coords, const _Float16* __restrict__ coords_h,
    const float* __restrict__ sq, const float* __restrict__ feats,
    float* __restrict__ agg, int* __restrict__ flags)
{
  __shared__ unsigned short sbuf[QB][CAP];   // 12288 B
  __shared__ int scnt[QB];                   //    64 B
  __shared__ float colminS[QB][NWAVES * 16]; //  8192 B
  __shared__ float taugS[QB];                //    64 B

  const int tid = threadIdx.x;       // 0..511
  const int lane = tid & 63;
  const int wave = tid >> 6;         // 0..7
  const int qbase = blockIdx.x * QB; // 16 queries/block
  const int n = lane & 15;           // candidate column within group
  const int quad = lane >> 4;        // 0..3

  if (tid < QB) scnt[tid] = 0;

  // A fragment: A[m=lane&15][k=quad*8+j]; zeros for k>=16 (quad>=2)
  f16x8 afrag = {0, 0, 0, 0, 0, 0, 0, 0};
  if (lane < 32) {
    const uint4 u = *(const uint4*)((const char*)coords_h + (qbase + n) * 32 + quad * 16);
    afrag = __builtin_bit_cast(f16x8, u);
  }
  // per-lane query rows: row = quad*4 + r -> sq[qbase+quad*4 .. +3]
  const float4 sqi4v = *(const float4*)&sq[qbase + quad * 4];
  const float sqi4[4] = {sqi4v.x, sqi4v.y, sqi4v.z, sqi4v.w};

  __syncthreads();   // scnt zeroed

  // ===================== Phase A: sample scan -> column minima ==============
  float lmin4[4] = {INFINITY, INFINITY, INFINITY, INFINITY};
  for (int g = wave; g < TAU_GROUPS; g += NWAVES) {
    const int j0 = g * 16;
    f16x8 bfrag = {0, 0, 0, 0, 0, 0, 0, 0};
    if (lane < 32) {
      const uint4 u = *(const uint4*)((const char*)coords_h + (j0 + n) * 32 + quad * 16);
      bfrag = __builtin_bit_cast(f16x8, u);
    }
    const float sqj = sq[j0 + n];
    f32x4 acc = {0.0f, 0.0f, 0.0f, 0.0f};
    acc = __builtin_amdgcn_mfma_f32_16x16x32_f16(afrag, bfrag, acc, 0, 0, 0);
    #pragma unroll
    for (int r = 0; r < 4; ++r) {
      float d2a = fmaf(-2.0f, acc[r], sqi4[r] + sqj);
      if (j0 + n == qbase + quad * 4 + r) d2a = INFINITY;  // exclude self
      lmin4[r] = fminf(lmin4[r], d2a);
    }
  }
  #pragma unroll
  for (int r = 0; r < 4; ++r)
    colminS[quad * 4 + r][wave * 16 + n] = lmin4[r];
  __syncthreads();

  // tau per query: 128 disjoint-subset minima -> pair-min 64 -> 16th order stat
  #pragma unroll
  for (int s = 0; s < 2; ++s) {
    const int q = wave * 2 + s;
    float v = fminf(colminS[q][lane], colminS[q][64 + lane]);
    #pragma unroll
    for (int k = 2; k <= 64; k <<= 1) {
      #pragma unroll
      for (int st = k >> 1; st >= 1; st >>= 1) {
        const float o = __shfl_xor(v, st);
        const bool keepMin = (((lane & st) == 0) == ((lane & k) == 0));
        const float mn = fminf(v, o), mx = fmaxf(v, o);
        v = keepMin ? mn : mx;
      }
    }
    const float tq = __shfl(v, 15) + MARGIN;   // sound gate
    if (lane == 0) taugS[q] = tq;
  }
  __syncthreads();

  float taug4[4];
  #pragma unroll
  for (int r = 0; r < 4; ++r) taug4[r] = taugS[quad * 4 + r];

  // ===================== Phase B: full MFMA scan, push survivors ============
  for (int g = wave; g < NGROUPS; g += NWAVES) {
    const int j0 = g * 16;
    f16x8 bfrag = {0, 0, 0, 0, 0, 0, 0, 0};
    if (lane < 32) {
      const uint4 u = *(const uint4*)((const char*)coords_h + (j0 + n) * 32 + quad * 16);
      bfrag = __builtin_bit_cast(f16x8, u);
    }
    const float sqj = sq[j0 + n];
    f32x4 acc = {0.0f, 0.0f, 0.0f, 0.0f};
    acc = __builtin_amdgcn_mfma_f32_16x16x32_f16(afrag, bfrag, acc, 0, 0, 0);
    #pragma unroll
    for (int r = 0; r < 4; ++r) {
      const float d2a = fmaf(-2.0f, acc[r], sqi4[r] + sqj);
      if (d2a <= taug4[r]) {             // self passes; filtered in Phase C
        const int row = quad * 4 + r;
        const int p = atomicAdd(&scnt[row], 1);
        if (p < CAP) sbuf[row][p] = (unsigned short)(j0 + n);
      }
    }
  }
  __syncthreads();

  // ===================== Phase C: exact fp32 re-score + top-16 ===============
  #pragma unroll
  for (int s = 0; s < 2; ++s) {
    const int lq = wave * 2 + s;         // query-in-block 0..15
    const int qg = qbase + lq;           // global query id
    const int cq = scnt[lq];
    const int nread = (cq < CAP) ? cq : CAP;

    float ci[16];
    {
      const float4* cp = (const float4*)(coords + qg * 16);
      *(float4*)&ci[0] = cp[0]; *(float4*)&ci[4] = cp[1];
      *(float4*)&ci[8] = cp[2]; *(float4*)&ci[12] = cp[3];
    }
    const float sqiq = sq[qg];

    u64 k6[6];
    #pragma unroll
    for (int t = 0; t < 6; ++t) k6[t] = ((u64)(0x7F000000u + t) << 32);
    u64 kmax6 = ((u64)0x7F000005u << 32);

    #pragma unroll
    for (int t = 0; t < CAP / 64; ++t) { // <=6 offers/lane: no eviction
      const int idx = t * 64 + lane;
      u64 key = ~0ull;
      if (idx < nread) {
        const int jj = sbuf[lq][idx];
        if (jj != qg) {
          const float4* cp = (const float4*)(coords + jj * 16);
          float cj[16];
          *(float4*)&cj[0]  = cp[0]; *(float4*)&cj[4]  = cp[1];
          *(float4*)&cj[8]  = cp[2]; *(float4*)&cj[12] = cp[3];
          float dot = 0.0f;
          #pragma unroll
          for (int d = 0; d < 16; ++d) dot = fmaf(ci[d], cj[d], dot);
          const float d2 = fmaxf(fmaf(-2.0f, dot, sqiq + sq[jj]), 0.0f);
          key = ((u64)__float_as_uint(d2) << 32) | (unsigned)jj;
        }
      }
      ins6(key, k6, kmax6);
    }

    u64 lmin = k6[0];
    #pragma unroll
    for (int t = 1; t < 6; ++t) lmin = (k6[t] < lmin) ? k6[t] : lmin;

    float aggv = 0.0f;
    for (int r = 0; r < KNN; ++r) {
      const u64 m = minbfly(lmin);
      if (lmin == m) {
        #pragma unroll
        for (int t = 0; t < 6; ++t) k6[t] = (k6[t] == m) ? ~0ull : k6[t];
        lmin = k6[0];
        #pragma unroll
        for (int t = 1; t < 6; ++t) lmin = (k6[t] < lmin) ? k6[t] : lmin;
      }
      const unsigned hi = (unsigned)(m >> 32);
      const bool ok = hi < 0x7F000000u;
      const float w = ok ? expf(-__uint_as_float(hi)) : 0.0f;
      const int jj = ok ? (int)(unsigned)(m & 0xFFFFFFFFull) : 0;
      aggv = fmaf(w, feats[jj * 64 + lane], aggv);
    }
    agg[qg * 64 + lane] = aggv;
    if (lane == 0) flags[qg] = (cq > CAP);
  }
}

// ---------------------------------------------------------------------------
// Kernel 2b: exact fallback for flagged (overflowed) queries — expected zero.
// ---------------------------------------------------------------------------
__global__ __launch_bounds__(256) void knn_fixup_kernel(
    const float* __restrict__ coords, const float* __restrict__ sq,
    const float* __restrict__ feats, const int* __restrict__ flags,
    float* __restrict__ agg)
{
  const int wave = threadIdx.x >> 6;
  const int lane = threadIdx.x & 63;
  const int i = blockIdx.x * 4 + wave;
  if (i >= N_PTS) return;
  if (!flags[i]) return;
  float ci[16];
  #pragma unroll
  for (int d = 0; d < 16; ++d) ci[d] = coords[i * 16 + d];
  const float sqi = sq[i];

  u64 k8a[8], k8b[8], kmaxA, kmaxB;
  #pragma unroll
  for (int t = 0; t < 8; ++t) {
    k8a[t] = ((u64)(0x7F000000u + t) << 32);
    k8b[t] = ((u64)(0x7F000000u + t) << 32);
  }
  kmaxA = ((u64)0x7F000007u << 32);
  kmaxB = ((u64)0x7F000007u << 32);

  const int niter = (N_PTS + 63) / 64;  // 188
  for (int t = 0; t < niter; ++t) {
    const int j = t * 64 + lane;
    float4 c0 = make_float4(0,0,0,0), c1 = c0, c2 = c0, c3 = c0;
    float sqj = 0.0f;
    if (j < N_PTS) {
      const float4* cp = (const float4*)(coords + j * 16);
      c0 = cp[0]; c1 = cp[1]; c2 = cp[2]; c3 = cp[3];
      sqj = sq[j];
    }
    float dot = ci[0]*c0.x + ci[1]*c0.y + ci[2]*c0.z + ci[3]*c0.w
              + ci[4]*c1.x + ci[5]*c1.y + ci[6]*c1.z + ci[7]*c1.w
              + ci[8]*c2.x + ci[9]*c2.y + ci[10]*c2.z + ci[11]*c2.w
              + ci[12]*c3.x + ci[13]*c3.y + ci[14]*c3.z + ci[15]*c3.w;
    float d2 = fmaxf(fmaf(-2.0f, dot, sqi + sqj), 0.0f);
    const unsigned hi = (j == i || j >= N_PTS) ? 0xFFFFFFFFu : __float_as_uint(d2);
    const u64 key = ((u64)hi << 32) | (unsigned)j;
    if (t & 1) ins8(key, k8a, kmaxA);
    else       ins8(key, k8b, kmaxB);
  }

  u64 tab[16];
  #pragma unroll
  for (int t = 0; t < 8; ++t) { tab[t] = k8a[t]; tab[8 + t] = k8b[t]; }
  u64 lmin = tab[0];
  #pragma unroll
  for (int t = 1; t < 16; ++t) lmin = (tab[t] < lmin) ? tab[t] : lmin;

  float aggv = 0.0f;
  u64 T16 = 0;
  for (int r = 0; r < KNN; ++r) {
    const u64 m = minbfly(lmin);
    if (lmin == m) {
      #pragma unroll
      for (int t = 0; t < 16; ++t) tab[t] = (tab[t] == m) ? ~0ull : tab[t];
      lmin = tab[0];
      #pragma unroll
      for (int t = 1; t < 16; ++t) lmin = (tab[t] < lmin) ? tab[t] : lmin;
    }
    const unsigned hi = (unsigned)(m >> 32);
    const bool ok = hi < 0x7F000000u;
    const float w = ok ? expf(-__uint_as_float(hi)) : 0.0f;
    const int jj = ok ? (int)(unsigned)(m & 0xFFFFFFFFull) : 0;
    aggv = fmaf(w, feats[jj * 64 + lane], aggv);
    T16 = m;
  }

  if (__any((kmaxA < T16) || (kmaxB < T16))) {
    aggv = 0.0f;
    u64 prev = 0;
    for (int r = 0; r < KNN; ++r) {
      u64 best = ~0ull;
      for (int j = lane; j < N_PTS; j += 64) {
        float dot = 0.0f;
        #pragma unroll
        for (int d = 0; d < 16; ++d) dot = fmaf(ci[d], coords[j * 16 + d], dot);
        const float d2 = fmaxf(fmaf(-2.0f, dot, sqi + sq[j]), 0.0f);
        const unsigned hi = (j == i) ? 0xFFFFFFFFu : __float_as_uint(d2);
        const u64 key = ((u64)hi << 32) | (unsigned)j;
        const bool cand = (r == 0) || (key > prev);
        if (cand && key < best) best = key;
      }
      const u64 m = minbfly(best);
      prev = m;
      const unsigned hi = (unsigned)(m >> 32);
      const bool ok = hi < 0x7F000000u;
      const float w = ok ? expf(-__uint_as_float(hi)) : 0.0f;
      const int jj = ok ? (int)(unsigned)(m & 0xFFFFFFFFull) : 0;
      aggv = fmaf(w, feats[jj * 64 + lane], aggv);
    }
  }
  agg[i * 64 + lane] = aggv;
}

// ---------------------------------------------------------------------------
// Kernel 3: out = concat(feats, agg) @ W_out + b_out. Two rows per thread
// share the Wo loads.
// ---------------------------------------------------------------------------
__global__ __launch_bounds__(256) void out_kernel(
    const float* __restrict__ feats, const float* __restrict__ agg,
    const float* __restrict__ Wo, const float* __restrict__ bo,
    float* __restrict__ out)
{
  const int idx = blockIdx.x * 256 + threadIdx.x;
  const int pr = idx >> 6, o = idx & 63;
  const int i0 = pr * 2;
  if (i0 >= N_PTS) return;
  float acc0 = bo[o], acc1 = acc0;
  #pragma unroll
  for (int f = 0; f < 64; ++f) {
    const float w1 = Wo[f * 64 + o];
    acc0 = fmaf(feats[i0 * 64 + f], w1, acc0);
    acc1 = fmaf(feats[(i0 + 1) * 64 + f], w1, acc1);
  }
  #pragma unroll
  for (int f = 0; f < 64; ++f) {
    const float w2 = Wo[(64 + f) * 64 + o];
    acc0 = fmaf(agg[i0 * 64 + f], w2, acc0);
    acc1 = fmaf(agg[(i0 + 1) * 64 + f], w2, acc1);
  }
  out[i0 * 64 + o] = acc0;
  out[(i0 + 1) * 64 + o] = acc1;
}

extern "C" void kernel_launch(void* const* d_in, const int* in_sizes, int n_in,
                              void* d_out, int out_size, void* d_ws, size_t ws_size,
                              hipStream_t stream) {
  const float* x  = (const float*)d_in[0];
  const float* Wf = (const float*)d_in[1];
  const float* bf = (const float*)d_in[2];
  const float* Wl = (const float*)d_in[3];
  const float* bl = (const float*)d_in[4];
  const float* Wo = (const float*)d_in[5];
  const float* bo = (const float*)d_in[6];
  float* out = (float*)d_out;

  char* ws = (char*)d_ws;
  float*     feats    = (float*)(ws);                 // 3,072,000 B
  float*     coords   = (float*)(ws + 3072000);       //   768,000 B
  float*     sqv      = (float*)(ws + 3840000);       //    48,000 B
  _Float16*  coords_h = (_Float16*)(ws + 3888000);    //   384,000 B
  float*     agg      = (float*)(ws + 4272000);       // 3,072,000 B
  int*       flags    = (int*)(ws + 7344000);         //    48,000 B

  encoder_kernel<<<3000, 256, 0, stream>>>(x, Wf, bf, Wl, bl, feats, coords, coords_h, sqv);
  knn_agg_kernel<<<N_PTS / QB, 512, 0, stream>>>(coords, coords_h, sqv, feats, agg, flags);
  knn_fixup_kernel<<<3000, 256, 0, stream>>>(coords, sqv, feats, flags, agg);
  out_kernel<<<1500, 256, 0, stream>>>(feats, agg, Wo, bo, out);
}

// Round 15
// 187.876 us; speedup vs baseline: 1.8311x; 1.1029x over previous
//
#include <hip/hip_runtime.h>
#include <math.h>

typedef unsigned long long u64;
typedef _Float16 f16x8 __attribute__((ext_vector_type(8)));
typedef float f32x4 __attribute__((ext_vector_type(4)));

#define N_PTS 12000
#define KNN 16
#define QB 16                            // queries per block (MFMA M dim)
#define NWAVES 8                         // waves per block (512 threads)
#define NGROUPS (N_PTS / 16)             // 750 candidate groups of 16
#define TAU_PTS 2048
#define TAU_GROUPS (TAU_PTS / 16)        // 128
#define CAP 384                          // survivor capacity; 6 offers/lane
#define MARGIN 0.08f                     // > 2*m, m = f16 d2 error bound ~0.032

// ---------------------------------------------------------------------------
// Kernel 1: encoders. feats = tanh(x@Wf+bf); coords = tanh(x@Wl+bl) fp32+f16;
// sq = |coords|^2. One wave per row.
// ---------------------------------------------------------------------------
__global__ __launch_bounds__(256) void encoder_kernel(
    const float* __restrict__ x, const float* __restrict__ Wf, const float* __restrict__ bf,
    const float* __restrict__ Wl, const float* __restrict__ bl,
    float* __restrict__ feats, float* __restrict__ coords, _Float16* __restrict__ coords_h,
    float* __restrict__ sq)
{
  const int wave = threadIdx.x >> 6;
  const int lane = threadIdx.x & 63;
  const int i = blockIdx.x * 4 + wave;
  if (i >= N_PTS) return;
  float xv = x[i * 64 + lane];
  float accf = bf[lane];
  float accc = bl[lane & 15];
  #pragma unroll
  for (int k = 0; k < 64; ++k) {
    float xk = __shfl(xv, k);
    accf = fmaf(xk, Wf[k * 64 + lane], accf);
    accc = fmaf(xk, Wl[k * 16 + (lane & 15)], accc);
  }
  feats[i * 64 + lane] = tanhf(accf);
  float c = tanhf(accc);
  float cc = (lane < 16) ? c * c : 0.0f;
  cc += __shfl_xor(cc, 1);
  cc += __shfl_xor(cc, 2);
  cc += __shfl_xor(cc, 4);
  cc += __shfl_xor(cc, 8);
  if (lane < 16) {
    coords[i * 16 + lane] = c;
    coords_h[i * 16 + lane] = (_Float16)c;
  }
  if (lane == 0) sq[i] = cc;
}

// ---------------------------------------------------------------------------
// u64-key helpers. Keys (f32bits(d2)<<32)|j unique; sentinels (0x7F00000t<<32)
// exceed any real key; ~0ull matches no slot.
// ---------------------------------------------------------------------------
__device__ __forceinline__ void ins6(u64 key, u64* k6, u64& kmax) {
  const u64 om = (key < kmax) ? kmax : ~0ull;
  #pragma unroll
  for (int t = 0; t < 6; ++t)
    k6[t] = (k6[t] == om) ? key : k6[t];
  u64 a = k6[0] > k6[1] ? k6[0] : k6[1];
  u64 b = k6[2] > k6[3] ? k6[2] : k6[3];
  u64 c = k6[4] > k6[5] ? k6[4] : k6[5];
  a = a > b ? a : b;
  kmax = a > c ? a : c;
}

__device__ __forceinline__ void ins8(u64 key, u64* k8, u64& kmax) {
  const u64 om = (key < kmax) ? kmax : ~0ull;
  #pragma unroll
  for (int t = 0; t < 8; ++t)
    k8[t] = (k8[t] == om) ? key : k8[t];
  u64 a = k8[0] > k8[1] ? k8[0] : k8[1];
  u64 b = k8[2] > k8[3] ? k8[2] : k8[3];
  u64 c = k8[4] > k8[5] ? k8[4] : k8[5];
  u64 d = k8[6] > k8[7] ? k8[6] : k8[7];
  a = a > b ? a : b;
  c = c > d ? c : d;
  kmax = a > c ? a : c;
}

__device__ __forceinline__ u64 shflx_u64(u64 v, int off) {
  int lo = __shfl_xor((int)(unsigned)v, off);
  int hi = __shfl_xor((int)(unsigned)(v >> 32), off);
  return ((u64)(unsigned)hi << 32) | (unsigned)lo;
}

__device__ __forceinline__ u64 minbfly(u64 m) {
  #pragma unroll
  for (int off = 32; off >= 1; off >>= 1) {
    u64 o = shflx_u64(m, off);
    m = (o < m) ? o : m;
  }
  return m;
}

// ---------------------------------------------------------------------------
// Kernel 2: MFMA-based KNN + gaussian aggregation + FUSED output GEMM.
// Block = 16 queries, 8 waves. A-frag = 16 queries f16 coords (K=16 in a
// K=32 MFMA, upper half zero). Per 16-cand group: one coalesced B-frag load
// + one mfma_f32_16x16x32_f16 -> 256 dots. C layout (m89-verified):
// col=lane&15 (candidate), row=(lane>>4)*4+reg (query).
// Phase A: per-(row,col) running min over 2048-pt sample (self->INF); 128
//   disjoint column minima per query -> pairwise-min to 64 -> 16th order
//   stat (bitonic) + MARGIN = sound gate.
// Phase B: full scan, gate, push u16 index into per-query block sbuf.
// Phase C: exact fp32 re-score + 6-slot tables + minbfly (exact; <=6
//   offers/lane); feats/agg rows stashed in LDS.
// Epilogue: block GEMM out = concat(feats,agg)@Wo + bo (16 rows, 2 cols/thr)
//   -- fusing this saved ~30us of dispatch+traffic in R12's A/B evidence.
// Only failure mode: survivor overflow -> flag -> fixup recomputes row+out.
// ---------------------------------------------------------------------------
__global__ __launch_bounds__(512) void knn_agg_kernel(
    const float* __restrict__ coords, const _Float16* __restrict__ coords_h,
    const float* __restrict__ sq, const float* __restrict__ feats,
    const float* __restrict__ Wo, const float* __restrict__ bo,
    float* __restrict__ out, int* __restrict__ flags)
{
  __shared__ unsigned short sbuf[QB][CAP];   // 12288 B
  __shared__ int scnt[QB];                   //    64 B
  __shared__ float colminS[QB][NWAVES * 16]; //  8192 B
  __shared__ float taugS[QB];                //    64 B
  __shared__ float featS[QB][64];            //  4096 B
  __shared__ float aggS[QB][64];             //  4096 B

  const int tid = threadIdx.x;       // 0..511
  const int lane = tid & 63;
  const int wave = tid >> 6;         // 0..7
  const int qbase = blockIdx.x * QB; // 16 queries/block
  const int n = lane & 15;           // candidate column within group
  const int quad = lane >> 4;        // 0..3

  if (tid < QB) scnt[tid] = 0;

  // A fragment: A[m=lane&15][k=quad*8+j]; zeros for k>=16 (quad>=2)
  f16x8 afrag = {0, 0, 0, 0, 0, 0, 0, 0};
  if (lane < 32) {
    const uint4 u = *(const uint4*)((const char*)coords_h + (qbase + n) * 32 + quad * 16);
    afrag = __builtin_bit_cast(f16x8, u);
  }
  // per-lane query rows: row = quad*4 + r -> sq[qbase+quad*4 .. +3]
  const float4 sqi4v = *(const float4*)&sq[qbase + quad * 4];
  const float sqi4[4] = {sqi4v.x, sqi4v.y, sqi4v.z, sqi4v.w};

  __syncthreads();   // scnt zeroed

  // ===================== Phase A: sample scan -> column minima ==============
  float lmin4[4] = {INFINITY, INFINITY, INFINITY, INFINITY};
  for (int g = wave; g < TAU_GROUPS; g += NWAVES) {
    const int j0 = g * 16;
    f16x8 bfrag = {0, 0, 0, 0, 0, 0, 0, 0};
    if (lane < 32) {
      const uint4 u = *(const uint4*)((const char*)coords_h + (j0 + n) * 32 + quad * 16);
      bfrag = __builtin_bit_cast(f16x8, u);
    }
    const float sqj = sq[j0 + n];
    f32x4 acc = {0.0f, 0.0f, 0.0f, 0.0f};
    acc = __builtin_amdgcn_mfma_f32_16x16x32_f16(afrag, bfrag, acc, 0, 0, 0);
    #pragma unroll
    for (int r = 0; r < 4; ++r) {
      float d2a = fmaf(-2.0f, acc[r], sqi4[r] + sqj);
      if (j0 + n == qbase + quad * 4 + r) d2a = INFINITY;  // exclude self
      lmin4[r] = fminf(lmin4[r], d2a);
    }
  }
  #pragma unroll
  for (int r = 0; r < 4; ++r)
    colminS[quad * 4 + r][wave * 16 + n] = lmin4[r];
  __syncthreads();

  // tau per query: 128 disjoint-subset minima -> pair-min 64 -> 16th order stat
  #pragma unroll
  for (int s = 0; s < 2; ++s) {
    const int q = wave * 2 + s;
    float v = fminf(colminS[q][lane], colminS[q][64 + lane]);
    #pragma unroll
    for (int k = 2; k <= 64; k <<= 1) {
      #pragma unroll
      for (int st = k >> 1; st >= 1; st >>= 1) {
        const float o = __shfl_xor(v, st);
        const bool keepMin = (((lane & st) == 0) == ((lane & k) == 0));
        const float mn = fminf(v, o), mx = fmaxf(v, o);
        v = keepMin ? mn : mx;
      }
    }
    const float tq = __shfl(v, 15) + MARGIN;   // sound gate
    if (lane == 0) taugS[q] = tq;
  }
  __syncthreads();

  float taug4[4];
  #pragma unroll
  for (int r = 0; r < 4; ++r) taug4[r] = taugS[quad * 4 + r];

  // ===================== Phase B: full MFMA scan, push survivors ============
  for (int g = wave; g < NGROUPS; g += NWAVES) {
    const int j0 = g * 16;
    f16x8 bfrag = {0, 0, 0, 0, 0, 0, 0, 0};
    if (lane < 32) {
      const uint4 u = *(const uint4*)((const char*)coords_h + (j0 + n) * 32 + quad * 16);
      bfrag = __builtin_bit_cast(f16x8, u);
    }
    const float sqj = sq[j0 + n];
    f32x4 acc = {0.0f, 0.0f, 0.0f, 0.0f};
    acc = __builtin_amdgcn_mfma_f32_16x16x32_f16(afrag, bfrag, acc, 0, 0, 0);
    #pragma unroll
    for (int r = 0; r < 4; ++r) {
      const float d2a = fmaf(-2.0f, acc[r], sqi4[r] + sqj);
      if (d2a <= taug4[r]) {             // self passes; filtered in Phase C
        const int row = quad * 4 + r;
        const int p = atomicAdd(&scnt[row], 1);
        if (p < CAP) sbuf[row][p] = (unsigned short)(j0 + n);
      }
    }
  }
  __syncthreads();

  // ===================== Phase C: exact fp32 re-score + top-16 ===============
  #pragma unroll
  for (int s = 0; s < 2; ++s) {
    const int lq = wave * 2 + s;         // query-in-block 0..15
    const int qg = qbase + lq;           // global query id
    const int cq = scnt[lq];
    const int nread = (cq < CAP) ? cq : CAP;

    float ci[16];
    {
      const float4* cp = (const float4*)(coords + qg * 16);
      *(float4*)&ci[0] = cp[0]; *(float4*)&ci[4] = cp[1];
      *(float4*)&ci[8] = cp[2]; *(float4*)&ci[12] = cp[3];
    }
    const float sqiq = sq[qg];

    u64 k6[6];
    #pragma unroll
    for (int t = 0; t < 6; ++t) k6[t] = ((u64)(0x7F000000u + t) << 32);
    u64 kmax6 = ((u64)0x7F000005u << 32);

    #pragma unroll
    for (int t = 0; t < CAP / 64; ++t) { // <=6 offers/lane: no eviction
      const int idx = t * 64 + lane;
      u64 key = ~0ull;
      if (idx < nread) {
        const int jj = sbuf[lq][idx];
        if (jj != qg) {
          const float4* cp = (const float4*)(coords + jj * 16);
          float cj[16];
          *(float4*)&cj[0]  = cp[0]; *(float4*)&cj[4]  = cp[1];
          *(float4*)&cj[8]  = cp[2]; *(float4*)&cj[12] = cp[3];
          float dot = 0.0f;
          #pragma unroll
          for (int d = 0; d < 16; ++d) dot = fmaf(ci[d], cj[d], dot);
          const float d2 = fmaxf(fmaf(-2.0f, dot, sqiq + sq[jj]), 0.0f);
          key = ((u64)__float_as_uint(d2) << 32) | (unsigned)jj;
        }
      }
      ins6(key, k6, kmax6);
    }

    u64 lmin = k6[0];
    #pragma unroll
    for (int t = 1; t < 6; ++t) lmin = (k6[t] < lmin) ? k6[t] : lmin;

    float aggv = 0.0f;
    for (int r = 0; r < KNN; ++r) {
      const u64 m = minbfly(lmin);
      if (lmin == m) {
        #pragma unroll
        for (int t = 0; t < 6; ++t) k6[t] = (k6[t] == m) ? ~0ull : k6[t];
        lmin = k6[0];
        #pragma unroll
        for (int t = 1; t < 6; ++t) lmin = (k6[t] < lmin) ? k6[t] : lmin;
      }
      const unsigned hi = (unsigned)(m >> 32);
      const bool ok = hi < 0x7F000000u;
      const float w = ok ? expf(-__uint_as_float(hi)) : 0.0f;
      const int jj = ok ? (int)(unsigned)(m & 0xFFFFFFFFull) : 0;
      aggv = fmaf(w, feats[jj * 64 + lane], aggv);
    }
    aggS[lq][lane] = aggv;
    featS[lq][lane] = feats[qg * 64 + lane];
    if (lane == 0) flags[qg] = (cq > CAP);
  }

  // ===================== Epilogue: fused out GEMM (16 rows/block) ============
  __syncthreads();
  const int row = tid >> 5;        // 0..15
  const int c0 = tid & 31;         // cols c0 and c0+32
  float acc0 = bo[c0], acc1 = bo[c0 + 32];
  #pragma unroll
  for (int f = 0; f < 64; ++f) {
    const float fv = featS[row][f];
    const float av = aggS[row][f];
    acc0 = fmaf(fv, Wo[f * 64 + c0],        acc0);
    acc1 = fmaf(fv, Wo[f * 64 + c0 + 32],   acc1);
    acc0 = fmaf(av, Wo[(64 + f) * 64 + c0],      acc0);
    acc1 = fmaf(av, Wo[(64 + f) * 64 + c0 + 32], acc1);
  }
  const int orow = qbase + row;
  out[orow * 64 + c0]      = acc0;
  out[orow * 64 + c0 + 32] = acc1;
}

// ---------------------------------------------------------------------------
// Kernel 2b: exact fallback for flagged (overflowed) queries — expected zero.
// Recomputes the full row: exact KNN + aggregation + fused out row.
// ---------------------------------------------------------------------------
__global__ __launch_bounds__(256) void knn_fixup_kernel(
    const float* __restrict__ coords, const float* __restrict__ sq,
    const float* __restrict__ feats, const int* __restrict__ flags,
    const float* __restrict__ Wo, const float* __restrict__ bo,
    float* __restrict__ out)
{
  const int wave = threadIdx.x >> 6;
  const int lane = threadIdx.x & 63;
  const int i = blockIdx.x * 4 + wave;
  if (i >= N_PTS) return;
  if (!flags[i]) return;
  float ci[16];
  #pragma unroll
  for (int d = 0; d < 16; ++d) ci[d] = coords[i * 16 + d];
  const float sqi = sq[i];

  u64 k8a[8], k8b[8], kmaxA, kmaxB;
  #pragma unroll
  for (int t = 0; t < 8; ++t) {
    k8a[t] = ((u64)(0x7F000000u + t) << 32);
    k8b[t] = ((u64)(0x7F000000u + t) << 32);
  }
  kmaxA = ((u64)0x7F000007u << 32);
  kmaxB = ((u64)0x7F000007u << 32);

  const int niter = (N_PTS + 63) / 64;  // 188
  for (int t = 0; t < niter; ++t) {
    const int j = t * 64 + lane;
    float4 c0 = make_float4(0,0,0,0), c1 = c0, c2 = c0, c3 = c0;
    float sqj = 0.0f;
    if (j < N_PTS) {
      const float4* cp = (const float4*)(coords + j * 16);
      c0 = cp[0]; c1 = cp[1]; c2 = cp[2]; c3 = cp[3];
      sqj = sq[j];
    }
    float dot = ci[0]*c0.x + ci[1]*c0.y + ci[2]*c0.z + ci[3]*c0.w
              + ci[4]*c1.x + ci[5]*c1.y + ci[6]*c1.z + ci[7]*c1.w
              + ci[8]*c2.x + ci[9]*c2.y + ci[10]*c2.z + ci[11]*c2.w
              + ci[12]*c3.x + ci[13]*c3.y + ci[14]*c3.z + ci[15]*c3.w;
    float d2 = fmaxf(fmaf(-2.0f, dot, sqi + sqj), 0.0f);
    const unsigned hi = (j == i || j >= N_PTS) ? 0xFFFFFFFFu : __float_as_uint(d2);
    const u64 key = ((u64)hi << 32) | (unsigned)j;
    if (t & 1) ins8(key, k8a, kmaxA);
    else       ins8(key, k8b, kmaxB);
  }

  u64 tab[16];
  #pragma unroll
  for (int t = 0; t < 8; ++t) { tab[t] = k8a[t]; tab[8 + t] = k8b[t]; }
  u64 lmin = tab[0];
  #pragma unroll
  for (int t = 1; t < 16; ++t) lmin = (tab[t] < lmin) ? tab[t] : lmin;

  float aggv = 0.0f;
  u64 T16 = 0;
  for (int r = 0; r < KNN; ++r) {
    const u64 m = minbfly(lmin);
    if (lmin == m) {
      #pragma unroll
      for (int t = 0; t < 16; ++t) tab[t] = (tab[t] == m) ? ~0ull : tab[t];
      lmin = tab[0];
      #pragma unroll
      for (int t = 1; t < 16; ++t) lmin = (tab[t] < lmin) ? tab[t] : lmin;
    }
    const unsigned hi = (unsigned)(m >> 32);
    const bool ok = hi < 0x7F000000u;
    const float w = ok ? expf(-__uint_as_float(hi)) : 0.0f;
    const int jj = ok ? (int)(unsigned)(m & 0xFFFFFFFFull) : 0;
    aggv = fmaf(w, feats[jj * 64 + lane], aggv);
    T16 = m;
  }

  if (__any((kmaxA < T16) || (kmaxB < T16))) {
    aggv = 0.0f;
    u64 prev = 0;
    for (int r = 0; r < KNN; ++r) {
      u64 best = ~0ull;
      for (int j = lane; j < N_PTS; j += 64) {
        float dot = 0.0f;
        #pragma unroll
        for (int d = 0; d < 16; ++d) dot = fmaf(ci[d], coords[j * 16 + d], dot);
        const float d2 = fmaxf(fmaf(-2.0f, dot, sqi + sq[j]), 0.0f);
        const unsigned hi = (j == i) ? 0xFFFFFFFFu : __float_as_uint(d2);
        const u64 key = ((u64)hi << 32) | (unsigned)j;
        const bool cand = (r == 0) || (key > prev);
        if (cand && key < best) best = key;
      }
      const u64 m = minbfly(best);
      prev = m;
      const unsigned hi = (unsigned)(m >> 32);
      const bool ok = hi < 0x7F000000u;
      const float w = ok ? expf(-__uint_as_float(hi)) : 0.0f;
      const int jj = ok ? (int)(unsigned)(m & 0xFFFFFFFFull) : 0;
      aggv = fmaf(w, feats[jj * 64 + lane], aggv);
    }
  }

  // fused output row
  const float fl = feats[i * 64 + lane];
  float acc = bo[lane];
  #pragma unroll
  for (int f = 0; f < 64; ++f) {
    acc = fmaf(__shfl(fl, f),   Wo[f * 64 + lane],        acc);
    acc = fmaf(__shfl(aggv, f), Wo[(64 + f) * 64 + lane], acc);
  }
  out[i * 64 + lane] = acc;
}

extern "C" void kernel_launch(void* const* d_in, const int* in_sizes, int n_in,
                              void* d_out, int out_size, void* d_ws, size_t ws_size,
                              hipStream_t stream) {
  const float* x  = (const float*)d_in[0];
  const float* Wf = (const float*)d_in[1];
  const float* bf = (const float*)d_in[2];
  const float* Wl = (const float*)d_in[3];
  const float* bl = (const float*)d_in[4];
  const float* Wo = (const float*)d_in[5];
  const float* bo = (const float*)d_in[6];
  float* out = (float*)d_out;

  char* ws = (char*)d_ws;
  float*     feats    = (float*)(ws);                 // 3,072,000 B
  float*     coords   = (float*)(ws + 3072000);       //   768,000 B
  float*     sqv      = (float*)(ws + 3840000);       //    48,000 B
  _Float16*  coords_h = (_Float16*)(ws + 3888000);    //   384,000 B
  int*       flags    = (int*)(ws + 4272000);         //    48,000 B

  encoder_kernel<<<3000, 256, 0, stream>>>(x, Wf, bf, Wl, bl, feats, coords, coords_h, sqv);
  knn_agg_kernel<<<N_PTS / QB, 512, 0, stream>>>(coords, coords_h, sqv, feats, Wo, bo, out, flags);
  knn_fixup_kernel<<<3000, 256, 0, stream>>>(coords, sqv, feats, flags, Wo, bo, out);
}

// Round 16
// 174.699 us; speedup vs baseline: 1.9692x; 1.0754x over previous
//
#include <hip/hip_runtime.h>
#include <math.h>

typedef unsigned long long u64;
typedef _Float16 f16x8 __attribute__((ext_vector_type(8)));
typedef float f32x16 __attribute__((ext_vector_type(16)));

#define N_PTS 12000
#define KNN 16
#define QB 16                            // queries per block (M rows 0..15 real, 16..31 zero-pad)
#define NWAVES 8                         // waves per block (512 threads)
#define NGROUPS32 (N_PTS / 32)           // 375 candidate groups of 32
#define TAU_PTS 2048
#define TAU_GROUPS32 (TAU_PTS / 32)      // 64
#define CAP 384                          // survivor capacity; 6 offers/lane
#define MARGIN 0.08f                     // > 2*m, m = f16 d2 error bound ~0.032

// ---------------------------------------------------------------------------
// Kernel 1: encoders. feats = tanh(x@Wf+bf); coords = tanh(x@Wl+bl) fp32+f16;
// sq = |coords|^2. One wave per row.
// ---------------------------------------------------------------------------
__global__ __launch_bounds__(256) void encoder_kernel(
    const float* __restrict__ x, const float* __restrict__ Wf, const float* __restrict__ bf,
    const float* __restrict__ Wl, const float* __restrict__ bl,
    float* __restrict__ feats, float* __restrict__ coords, _Float16* __restrict__ coords_h,
    float* __restrict__ sq)
{
  const int wave = threadIdx.x >> 6;
  const int lane = threadIdx.x & 63;
  const int i = blockIdx.x * 4 + wave;
  if (i >= N_PTS) return;
  float xv = x[i * 64 + lane];
  float accf = bf[lane];
  float accc = bl[lane & 15];
  #pragma unroll
  for (int k = 0; k < 64; ++k) {
    float xk = __shfl(xv, k);
    accf = fmaf(xk, Wf[k * 64 + lane], accf);
    accc = fmaf(xk, Wl[k * 16 + (lane & 15)], accc);
  }
  feats[i * 64 + lane] = tanhf(accf);
  float c = tanhf(accc);
  float cc = (lane < 16) ? c * c : 0.0f;
  cc += __shfl_xor(cc, 1);
  cc += __shfl_xor(cc, 2);
  cc += __shfl_xor(cc, 4);
  cc += __shfl_xor(cc, 8);
  if (lane < 16) {
    coords[i * 16 + lane] = c;
    coords_h[i * 16 + lane] = (_Float16)c;
  }
  if (lane == 0) sq[i] = cc;
}

// ---------------------------------------------------------------------------
// u64-key helpers. Keys (f32bits(d2)<<32)|j unique; sentinels (0x7F00000t<<32)
// exceed any real key; ~0ull matches no slot.
// ---------------------------------------------------------------------------
__device__ __forceinline__ void ins6(u64 key, u64* k6, u64& kmax) {
  const u64 om = (key < kmax) ? kmax : ~0ull;
  #pragma unroll
  for (int t = 0; t < 6; ++t)
    k6[t] = (k6[t] == om) ? key : k6[t];
  u64 a = k6[0] > k6[1] ? k6[0] : k6[1];
  u64 b = k6[2] > k6[3] ? k6[2] : k6[3];
  u64 c = k6[4] > k6[5] ? k6[4] : k6[5];
  a = a > b ? a : b;
  kmax = a > c ? a : c;
}

__device__ __forceinline__ void ins8(u64 key, u64* k8, u64& kmax) {
  const u64 om = (key < kmax) ? kmax : ~0ull;
  #pragma unroll
  for (int t = 0; t < 8; ++t)
    k8[t] = (k8[t] == om) ? key : k8[t];
  u64 a = k8[0] > k8[1] ? k8[0] : k8[1];
  u64 b = k8[2] > k8[3] ? k8[2] : k8[3];
  u64 c = k8[4] > k8[5] ? k8[4] : k8[5];
  u64 d = k8[6] > k8[7] ? k8[6] : k8[7];
  a = a > b ? a : b;
  c = c > d ? c : d;
  kmax = a > c ? a : c;
}

__device__ __forceinline__ u64 shflx_u64(u64 v, int off) {
  int lo = __shfl_xor((int)(unsigned)v, off);
  int hi = __shfl_xor((int)(unsigned)(v >> 32), off);
  return ((u64)(unsigned)hi << 32) | (unsigned)lo;
}

__device__ __forceinline__ u64 minbfly(u64 m) {
  #pragma unroll
  for (int off = 32; off >= 1; off >>= 1) {
    u64 o = shflx_u64(m, off);
    m = (o < m) ? o : m;
  }
  return m;
}

// ---------------------------------------------------------------------------
// Kernel 2: 32x32x16-MFMA KNN + gaussian aggregation + fused output GEMM.
// Block = 16 queries (A rows 0..15 real, 16..31 zero), 8 waves. Per 32-cand
// group: one full-wave coalesced B load (1KB/instr) + one
// mfma_f32_32x32x16_f16 (K=16 exact, no zero-K waste) -> 512 useful dots.
// C layout (m74/m101-verified): col=lane&31, row=(reg&3)+8*(reg>>2)+4*(lane>>5);
// regs with row<16 (blk<2) are the 8 valid checks per lane.
// Phase A: per-lane minima -> 64 disjoint 32-pt-subset cell minima via LDS
//   atomicMin on clamped f32 bits; tau = 16th order stat (bitonic) + MARGIN.
//   SOUND: 16 smallest cells are 16 distinct points => bound >= true 16th.
// Phase B: full scan, gate, push u16 index. Phase C: exact fp32 re-score +
//   6-slot tables + minbfly (<=6 offers/lane: no eviction -> exact).
// Epilogue: block GEMM out = concat(feats,agg)@Wo + bo.
// Only failure mode: survivor overflow -> flag -> fixup recomputes row+out.
// ---------------------------------------------------------------------------
__global__ __launch_bounds__(512) void knn_agg_kernel(
    const float* __restrict__ coords, const _Float16* __restrict__ coords_h,
    const float* __restrict__ sq, const float* __restrict__ feats,
    const float* __restrict__ Wo, const float* __restrict__ bo,
    float* __restrict__ out, int* __restrict__ flags)
{
  __shared__ unsigned short sbuf[QB][CAP];   // 12288 B
  __shared__ int scnt[QB];                   //    64 B
  __shared__ unsigned colminS[QB][64];       //  4096 B
  __shared__ float taugS[QB];                //    64 B
  __shared__ float featS[QB][64];            //  4096 B
  __shared__ float aggS[QB][64];             //  4096 B

  const int tid = threadIdx.x;       // 0..511
  const int lane = tid & 63;
  const int wave = tid >> 6;         // 0..7
  const int qbase = blockIdx.x * QB;
  const int mcol = lane & 31;        // A row / B col
  const int half = lane >> 5;        // k-half (0: k=0..7, 1: k=8..15)

  if (tid < QB) scnt[tid] = 0;
  #pragma unroll
  for (int t = tid; t < QB * 64; t += 512)
    ((unsigned*)colminS)[t] = 0x7F800000u;   // +INF bits

  // A fragment: A[m=lane&31][k=half*8+j]; rows >=16 zero (padding)
  f16x8 afrag = {0, 0, 0, 0, 0, 0, 0, 0};
  if (mcol < QB) {
    const uint4 u = *(const uint4*)((const char*)coords_h + (qbase + mcol) * 32 + half * 16);
    afrag = __builtin_bit_cast(f16x8, u);
  }
  // rows handled by this lane: row(r) = (r>>2)*8 + 4*half + (r&3), r=0..7
  float sqi8[8];
  #pragma unroll
  for (int blk = 0; blk < 2; ++blk) {
    const float4 v = *(const float4*)&sq[qbase + blk * 8 + 4 * half];
    sqi8[blk * 4 + 0] = v.x; sqi8[blk * 4 + 1] = v.y;
    sqi8[blk * 4 + 2] = v.z; sqi8[blk * 4 + 3] = v.w;
  }
  __syncthreads();   // scnt + colminS init visible

  // ===================== Phase A: sample scan -> cell minima =================
  float lmin8[8] = {INFINITY, INFINITY, INFINITY, INFINITY,
                    INFINITY, INFINITY, INFINITY, INFINITY};
  for (int g = wave; g < TAU_GROUPS32; g += NWAVES) {
    const int j0 = g * 32;
    const uint4 u = *(const uint4*)((const char*)coords_h + (j0 + mcol) * 32 + half * 16);
    const f16x8 bfrag = __builtin_bit_cast(f16x8, u);
    const float sqj = sq[j0 + mcol];
    f32x16 acc = {0.0f};
    acc = __builtin_amdgcn_mfma_f32_32x32x16_f16(afrag, bfrag, acc, 0, 0, 0);
    #pragma unroll
    for (int r = 0; r < 8; ++r) {
      const int row = (r >> 2) * 8 + 4 * half + (r & 3);
      float d2a = fmaf(-2.0f, acc[r], sqi8[r] + sqj);
      if (j0 + mcol == qbase + row) d2a = INFINITY;  // exclude self
      lmin8[r] = fminf(lmin8[r], d2a);
    }
  }
  {
    const int cell = mcol * 2 + (wave >> 2);  // 64 disjoint 32-pt subsets
    #pragma unroll
    for (int r = 0; r < 8; ++r) {
      const int row = (r >> 2) * 8 + 4 * half + (r & 3);
      atomicMin(&colminS[row][cell], __float_as_uint(fmaxf(lmin8[r], 0.0f)));
    }
  }
  __syncthreads();

  // tau per query: 16th order stat of the 64 cell minima (bitonic, lane 15)
  #pragma unroll
  for (int s = 0; s < 2; ++s) {
    const int q = wave * 2 + s;
    float v = __uint_as_float(colminS[q][lane]);
    #pragma unroll
    for (int k = 2; k <= 64; k <<= 1) {
      #pragma unroll
      for (int st = k >> 1; st >= 1; st >>= 1) {
        const float o = __shfl_xor(v, st);
        const bool keepMin = (((lane & st) == 0) == ((lane & k) == 0));
        const float mn = fminf(v, o), mx = fmaxf(v, o);
        v = keepMin ? mn : mx;
      }
    }
    const float tq = __shfl(v, 15) + MARGIN;   // sound gate
    if (lane == 0) taugS[q] = tq;
  }
  __syncthreads();

  float taug8[8];
  #pragma unroll
  for (int r = 0; r < 8; ++r)
    taug8[r] = taugS[(r >> 2) * 8 + 4 * half + (r & 3)];

  // ===================== Phase B: full MFMA scan, push survivors ============
  for (int g = wave; g < NGROUPS32; g += NWAVES) {
    const int j0 = g * 32;
    const uint4 u = *(const uint4*)((const char*)coords_h + (j0 + mcol) * 32 + half * 16);
    const f16x8 bfrag = __builtin_bit_cast(f16x8, u);
    const float sqj = sq[j0 + mcol];
    f32x16 acc = {0.0f};
    acc = __builtin_amdgcn_mfma_f32_32x32x16_f16(afrag, bfrag, acc, 0, 0, 0);
    #pragma unroll
    for (int r = 0; r < 8; ++r) {
      const float d2a = fmaf(-2.0f, acc[r], sqi8[r] + sqj);
      if (d2a <= taug8[r]) {             // self passes; filtered in Phase C
        const int row = (r >> 2) * 8 + 4 * half + (r & 3);
        const int p = atomicAdd(&scnt[row], 1);
        if (p < CAP) sbuf[row][p] = (unsigned short)(j0 + mcol);
      }
    }
  }
  __syncthreads();

  // ===================== Phase C: exact fp32 re-score + top-16 ===============
  #pragma unroll
  for (int s = 0; s < 2; ++s) {
    const int lq = wave * 2 + s;         // query-in-block 0..15
    const int qg = qbase + lq;           // global query id
    const int cq = scnt[lq];
    const int nread = (cq < CAP) ? cq : CAP;

    float ci[16];
    {
      const float4* cp = (const float4*)(coords + qg * 16);
      *(float4*)&ci[0] = cp[0]; *(float4*)&ci[4] = cp[1];
      *(float4*)&ci[8] = cp[2]; *(float4*)&ci[12] = cp[3];
    }
    const float sqiq = sq[qg];

    u64 k6[6];
    #pragma unroll
    for (int t = 0; t < 6; ++t) k6[t] = ((u64)(0x7F000000u + t) << 32);
    u64 kmax6 = ((u64)0x7F000005u << 32);

    #pragma unroll
    for (int t = 0; t < CAP / 64; ++t) { // <=6 offers/lane: no eviction
      const int idx = t * 64 + lane;
      u64 key = ~0ull;
      if (idx < nread) {
        const int jj = sbuf[lq][idx];
        if (jj != qg) {
          const float4* cp = (const float4*)(coords + jj * 16);
          float cj[16];
          *(float4*)&cj[0]  = cp[0]; *(float4*)&cj[4]  = cp[1];
          *(float4*)&cj[8]  = cp[2]; *(float4*)&cj[12] = cp[3];
          float dot = 0.0f;
          #pragma unroll
          for (int d = 0; d < 16; ++d) dot = fmaf(ci[d], cj[d], dot);
          const float d2 = fmaxf(fmaf(-2.0f, dot, sqiq + sq[jj]), 0.0f);
          key = ((u64)__float_as_uint(d2) << 32) | (unsigned)jj;
        }
      }
      ins6(key, k6, kmax6);
    }

    u64 lmin = k6[0];
    #pragma unroll
    for (int t = 1; t < 6; ++t) lmin = (k6[t] < lmin) ? k6[t] : lmin;

    float aggv = 0.0f;
    for (int r = 0; r < KNN; ++r) {
      const u64 m = minbfly(lmin);
      if (lmin == m) {
        #pragma unroll
        for (int t = 0; t < 6; ++t) k6[t] = (k6[t] == m) ? ~0ull : k6[t];
        lmin = k6[0];
        #pragma unroll
        for (int t = 1; t < 6; ++t) lmin = (k6[t] < lmin) ? k6[t] : lmin;
      }
      const unsigned hi = (unsigned)(m >> 32);
      const bool ok = hi < 0x7F000000u;
      const float w = ok ? expf(-__uint_as_float(hi)) : 0.0f;
      const int jj = ok ? (int)(unsigned)(m & 0xFFFFFFFFull) : 0;
      aggv = fmaf(w, feats[jj * 64 + lane], aggv);
    }
    aggS[lq][lane] = aggv;
    featS[lq][lane] = feats[qg * 64 + lane];
    if (lane == 0) flags[qg] = (cq > CAP);
  }

  // ===================== Epilogue: fused out GEMM (16 rows/block) ============
  __syncthreads();
  const int row = tid >> 5;        // 0..15
  const int c0 = tid & 31;         // cols c0 and c0+32
  float acc0 = bo[c0], acc1 = bo[c0 + 32];
  #pragma unroll
  for (int f = 0; f < 64; ++f) {
    const float fv = featS[row][f];
    const float av = aggS[row][f];
    acc0 = fmaf(fv, Wo[f * 64 + c0],        acc0);
    acc1 = fmaf(fv, Wo[f * 64 + c0 + 32],   acc1);
    acc0 = fmaf(av, Wo[(64 + f) * 64 + c0],      acc0);
    acc1 = fmaf(av, Wo[(64 + f) * 64 + c0 + 32], acc1);
  }
  const int orow = qbase + row;
  out[orow * 64 + c0]      = acc0;
  out[orow * 64 + c0 + 32] = acc1;
}

// ---------------------------------------------------------------------------
// Kernel 2b: exact fallback for flagged (overflowed) queries — expected zero.
// Recomputes the full row: exact KNN + aggregation + fused out row.
// ---------------------------------------------------------------------------
__global__ __launch_bounds__(256) void knn_fixup_kernel(
    const float* __restrict__ coords, const float* __restrict__ sq,
    const float* __restrict__ feats, const int* __restrict__ flags,
    const float* __restrict__ Wo, const float* __restrict__ bo,
    float* __restrict__ out)
{
  const int wave = threadIdx.x >> 6;
  const int lane = threadIdx.x & 63;
  const int i = blockIdx.x * 4 + wave;
  if (i >= N_PTS) return;
  if (!flags[i]) return;
  float ci[16];
  #pragma unroll
  for (int d = 0; d < 16; ++d) ci[d] = coords[i * 16 + d];
  const float sqi = sq[i];

  u64 k8a[8], k8b[8], kmaxA, kmaxB;
  #pragma unroll
  for (int t = 0; t < 8; ++t) {
    k8a[t] = ((u64)(0x7F000000u + t) << 32);
    k8b[t] = ((u64)(0x7F000000u + t) << 32);
  }
  kmaxA = ((u64)0x7F000007u << 32);
  kmaxB = ((u64)0x7F000007u << 32);

  const int niter = (N_PTS + 63) / 64;  // 188
  for (int t = 0; t < niter; ++t) {
    const int j = t * 64 + lane;
    float4 c0 = make_float4(0,0,0,0), c1 = c0, c2 = c0, c3 = c0;
    float sqj = 0.0f;
    if (j < N_PTS) {
      const float4* cp = (const float4*)(coords + j * 16);
      c0 = cp[0]; c1 = cp[1]; c2 = cp[2]; c3 = cp[3];
      sqj = sq[j];
    }
    float dot = ci[0]*c0.x + ci[1]*c0.y + ci[2]*c0.z + ci[3]*c0.w
              + ci[4]*c1.x + ci[5]*c1.y + ci[6]*c1.z + ci[7]*c1.w
              + ci[8]*c2.x + ci[9]*c2.y + ci[10]*c2.z + ci[11]*c2.w
              + ci[12]*c3.x + ci[13]*c3.y + ci[14]*c3.z + ci[15]*c3.w;
    float d2 = fmaxf(fmaf(-2.0f, dot, sqi + sqj), 0.0f);
    const unsigned hi = (j == i || j >= N_PTS) ? 0xFFFFFFFFu : __float_as_uint(d2);
    const u64 key = ((u64)hi << 32) | (unsigned)j;
    if (t & 1) ins8(key, k8a, kmaxA);
    else       ins8(key, k8b, kmaxB);
  }

  u64 tab[16];
  #pragma unroll
  for (int t = 0; t < 8; ++t) { tab[t] = k8a[t]; tab[8 + t] = k8b[t]; }
  u64 lmin = tab[0];
  #pragma unroll
  for (int t = 1; t < 16; ++t) lmin = (tab[t] < lmin) ? tab[t] : lmin;

  float aggv = 0.0f;
  u64 T16 = 0;
  for (int r = 0; r < KNN; ++r) {
    const u64 m = minbfly(lmin);
    if (lmin == m) {
      #pragma unroll
      for (int t = 0; t < 16; ++t) tab[t] = (tab[t] == m) ? ~0ull : tab[t];
      lmin = tab[0];
      #pragma unroll
      for (int t = 1; t < 16; ++t) lmin = (tab[t] < lmin) ? tab[t] : lmin;
    }
    const unsigned hi = (unsigned)(m >> 32);
    const bool ok = hi < 0x7F000000u;
    const float w = ok ? expf(-__uint_as_float(hi)) : 0.0f;
    const int jj = ok ? (int)(unsigned)(m & 0xFFFFFFFFull) : 0;
    aggv = fmaf(w, feats[jj * 64 + lane], aggv);
    T16 = m;
  }

  if (__any((kmaxA < T16) || (kmaxB < T16))) {
    aggv = 0.0f;
    u64 prev = 0;
    for (int r = 0; r < KNN; ++r) {
      u64 best = ~0ull;
      for (int j = lane; j < N_PTS; j += 64) {
        float dot = 0.0f;
        #pragma unroll
        for (int d = 0; d < 16; ++d) dot = fmaf(ci[d], coords[j * 16 + d], dot);
        const float d2 = fmaxf(fmaf(-2.0f, dot, sqi + sq[j]), 0.0f);
        const unsigned hi = (j == i) ? 0xFFFFFFFFu : __float_as_uint(d2);
        const u64 key = ((u64)hi << 32) | (unsigned)j;
        const bool cand = (r == 0) || (key > prev);
        if (cand && key < best) best = key;
      }
      const u64 m = minbfly(best);
      prev = m;
      const unsigned hi = (unsigned)(m >> 32);
      const bool ok = hi < 0x7F000000u;
      const float w = ok ? expf(-__uint_as_float(hi)) : 0.0f;
      const int jj = ok ? (int)(unsigned)(m & 0xFFFFFFFFull) : 0;
      aggv = fmaf(w, feats[jj * 64 + lane], aggv);
    }
  }

  // fused output row
  const float fl = feats[i * 64 + lane];
  float acc = bo[lane];
  #pragma unroll
  for (int f = 0; f < 64; ++f) {
    acc = fmaf(__shfl(fl, f),   Wo[f * 64 + lane],        acc);
    acc = fmaf(__shfl(aggv, f), Wo[(64 + f) * 64 + lane], acc);
  }
  out[i * 64 + lane] = acc;
}

extern "C" void kernel_launch(void* const* d_in, const int* in_sizes, int n_in,
                              void* d_out, int out_size, void* d_ws, size_t ws_size,
                              hipStream_t stream) {
  const float* x  = (const float*)d_in[0];
  const float* Wf = (const float*)d_in[1];
  const float* bf = (const float*)d_in[2];
  const float* Wl = (const float*)d_in[3];
  const float* bl = (const float*)d_in[4];
  const float* Wo = (const float*)d_in[5];
  const float* bo = (const float*)d_in[6];
  float* out = (float*)d_out;

  char* ws = (char*)d_ws;
  float*     feats    = (float*)(ws);                 // 3,072,000 B
  float*     coords   = (float*)(ws + 3072000);       //   768,000 B
  float*     sqv      = (float*)(ws + 3840000);       //    48,000 B
  _Float16*  coords_h = (_Float16*)(ws + 3888000);    //   384,000 B
  int*       flags    = (int*)(ws + 4272000);         //    48,000 B

  encoder_kernel<<<3000, 256, 0, stream>>>(x, Wf, bf, Wl, bl, feats, coords, coords_h, sqv);
  knn_agg_kernel<<<N_PTS / QB, 512, 0, stream>>>(coords, coords_h, sqv, feats, Wo, bo, out, flags);
  knn_fixup_kernel<<<3000, 256, 0, stream>>>(coords, sqv, feats, flags, Wo, bo, out);
}